// Round 7
// baseline (3115.959 us; speedup 1.0000x reference)
//
#include <hip/hip_runtime.h>
#include <hip/hip_bf16.h>

#define NMESH 50000
#define GRIDN 32768
#define NEDGE 131072
#define HID 384
#define CHUNK 32768
#define NCHUNK 4

using f32x4 = __attribute__((ext_vector_type(4))) float;
using bfrag = __attribute__((ext_vector_type(8))) short;
using i32x4 = __attribute__((ext_vector_type(4))) int;

__device__ __forceinline__ float gelu_f(float v) {
    return 0.5f * v * (1.0f + erff(v * 0.70710678118654752f));
}

__device__ __forceinline__ void load_lds16(const void* g, void* l) {
    __builtin_amdgcn_global_load_lds(
        (const __attribute__((address_space(1))) void*)g,
        (__attribute__((address_space(3))) void*)l,
        16, 0, 0);
}

// bijective XCD-chunking swizzle (m204)
__device__ __forceinline__ void xcd_swizzle(int& bx, int& by) {
    int gx = gridDim.x;
    int nwg = gx * gridDim.y;
    int l = blockIdx.y * gx + blockIdx.x;
    int q = nwg >> 3, r = nwg & 7;
    int xcd = l & 7, pos = l >> 3;
    int nl = (xcd < r ? xcd * (q + 1) : r * (q + 1) + (xcd - r) * q) + pos;
    by = nl / gx;
    bx = nl - by * gx;
}

// ---------------- weight transpose + bf16 cast: Wt[n*K+k] = W[k*N+n] ----------------
__global__ void transpose_to_bf16(const float* __restrict__ w, __hip_bfloat16* __restrict__ wt,
                                  int K, int N) {
    int idx = blockIdx.x * blockDim.x + threadIdx.x;
    if (idx >= K * N) return;
    int n = idx / K;
    int k = idx - n * K;
    wt[idx] = __float2bfloat16(w[(size_t)k * N + n]);
}

// ---------------- sincos positional embedding ----------------
__global__ void embed_kernel(const float* __restrict__ pos, __hip_bfloat16* __restrict__ outp,
                             int n, int stride, int coloff) {
    int idx = blockIdx.x * blockDim.x + threadIdx.x;
    if (idx >= n * 96) return;
    int nn = idx / 96;
    int rr = idx - nn * 96;
    int d = rr >> 5;
    int k = rr & 31;
    float v = pos[nn * 3 + d];
    float omega = expf(-0.28782313662425575f * (float)k);  // ln(10000)/32
    float a = v * omega;
    __hip_bfloat16* o = outp + (size_t)nn * stride + coloff + d * 64 + k;
    o[0]  = __float2bfloat16(sinf(a));
    o[32] = __float2bfloat16(cosf(a));
}

// ---------------- layer 1: h1 = gelu(x @ w1 + b1), K=16 ----------------
__global__ void lin1_kernel(const float* __restrict__ x, const float* __restrict__ w,
                            const float* __restrict__ b, __hip_bfloat16* __restrict__ h1) {
    int idx = blockIdx.x * blockDim.x + threadIdx.x;
    if (idx >= NMESH * HID) return;
    int m = idx / HID;
    int n = idx - m * HID;
    float acc = b[n];
    const float* xr = x + m * 16;
    #pragma unroll
    for (int k = 0; k < 16; k++) acc = fmaf(xr[k], w[k * HID + n], acc);
    h1[idx] = __float2bfloat16(gelu_f(acc));
}

// ======================================================================
// 256x256-tile bf16 MFMA GEMM (for N multiple of 256): 8 waves (2Mx4N),
// per-wave output 128x64 -> 32 MFMA/wave/K-step (BK=32). Double-buffered
// LDS (64KB -> 2 blocks/CU), global_load_lds with pre-swizzled source:
// physical slot p holds (row=p>>2, kc=(p&3)^((p>>3)&3)); fragment reads at
// kqx = kq^((lr>>1)&3) are conflict-free (verified: 0 conflicts @128^2).
// ======================================================================
template<bool GATHER, bool GELU>
__launch_bounds__(512, 4)
__global__ void mfma_gemm256(const __hip_bfloat16* __restrict__ A,
                             const __hip_bfloat16* __restrict__ Wt,
                             const float* __restrict__ bias,
                             __hip_bfloat16* __restrict__ C,
                             int M, int N, int K, int ldc,
                             const int* __restrict__ edges,
                             const __hip_bfloat16* __restrict__ meshf,
                             const __hip_bfloat16* __restrict__ gridf) {
    __shared__ __align__(16) __hip_bfloat16 As[2][8192];
    __shared__ __align__(16) __hip_bfloat16 Bs[2][8192];

    const int t = threadIdx.x;       // 0..511
    const int lane = t & 63;
    const int wave = t >> 6;         // 0..7
    const int wm0 = (wave >> 2) * 128;   // 2 row-groups
    const int wn0 = (wave & 3) * 64;     // 4 col-groups

    int bx, by;
    xcd_swizzle(bx, by);
    const int row0 = by * 256;
    const int col0 = bx * 256;

    // staging: thread t covers physical slots t (rows 0..127) and t+512 (rows 128..255)
    const int rS0 = t >> 2;
    const int rS1 = rS0 + 128;
    const int kcS = (t & 3) ^ ((t >> 3) & 3);

    const __hip_bfloat16 *aP0, *aP1, *aQ0 = nullptr, *aQ1 = nullptr;
    if constexpr (GATHER) {
        int e0 = min(row0 + rS0, M - 1);
        int e1 = min(row0 + rS1, M - 1);
        aP0 = meshf + (size_t)edges[2 * e0 + 1] * 576;
        aQ0 = gridf + (size_t)edges[2 * e0 + 0] * 192;
        aP1 = meshf + (size_t)edges[2 * e1 + 1] * 576;
        aQ1 = gridf + (size_t)edges[2 * e1 + 0] * 192;
    } else {
        aP0 = A + (size_t)min(row0 + rS0, M - 1) * K;
        aP1 = A + (size_t)min(row0 + rS1, M - 1) * K;
    }
    const __hip_bfloat16* bP0 = Wt + (size_t)(col0 + rS0) * K;
    const __hip_bfloat16* bP1 = Wt + (size_t)(col0 + rS1) * K;

    // wave-uniform LDS dest byte bases (HW adds lane*16)
    const int off0 = (wave * 64) * 16;
    const int off1 = (512 + wave * 64) * 16;

    f32x4 acc[8][4] = {};

    const int kq = lane >> 4;
    const int lr = lane & 15;
    const int kqx = kq ^ ((lr >> 1) & 3);
    // fragment read element base: (rowbase+lr)*32 + kqx*8; fragment i at +i*512
    const int rdA = (wm0 + lr) * 32 + kqx * 8;
    const int rdB = (wn0 + lr) * 32 + kqx * 8;

    const int nsteps = K >> 5;

    auto stage = [&](int ks, int buf) {
        int k = ks * 32 + kcS * 8;
        const __hip_bfloat16 *sa0, *sa1;
        if constexpr (GATHER) {
            sa0 = (k < 576) ? (aP0 + k) : (aQ0 + (k - 576));
            sa1 = (k < 576) ? (aP1 + k) : (aQ1 + (k - 576));
        } else {
            sa0 = aP0 + k;
            sa1 = aP1 + k;
        }
        load_lds16(sa0, (char*)As[buf] + off0);
        load_lds16(sa1, (char*)As[buf] + off1);
        load_lds16(bP0 + k, (char*)Bs[buf] + off0);
        load_lds16(bP1 + k, (char*)Bs[buf] + off1);
    };

    stage(0, 0);
    __syncthreads();

    int cur = 0;
    for (int ks = 0; ks < nsteps; ks++) {
        if (ks + 1 < nsteps) stage(ks + 1, cur ^ 1);  // issue next-tile loads first

        bfrag aF[8], bF[4];
        #pragma unroll
        for (int i = 0; i < 8; i++)
            aF[i] = *reinterpret_cast<const bfrag*>(&As[cur][rdA + i * 512]);
        #pragma unroll
        for (int j = 0; j < 4; j++)
            bF[j] = *reinterpret_cast<const bfrag*>(&Bs[cur][rdB + j * 512]);
        #pragma unroll
        for (int i = 0; i < 8; i++) {
            #pragma unroll
            for (int j = 0; j < 4; j++) {
                acc[i][j] = __builtin_amdgcn_mfma_f32_16x16x32_bf16(aF[i], bF[j], acc[i][j], 0, 0, 0);
            }
        }
        __syncthreads();
        cur ^= 1;
    }

    // C/D layout: col = lane&15, row = (lane>>4)*4 + reg
    #pragma unroll
    for (int i = 0; i < 8; i++) {
        #pragma unroll
        for (int j = 0; j < 4; j++) {
            #pragma unroll
            for (int r = 0; r < 4; r++) {
                int row = row0 + wm0 + i * 16 + kq * 4 + r;
                int col = col0 + wn0 + j * 16 + lr;
                if (row < M) {
                    float v = acc[i][j][r] + bias[col];
                    if constexpr (GELU) v = gelu_f(v);
                    C[(size_t)row * ldc + col] = __float2bfloat16(v);
                }
            }
        }
    }
}

// ---------------- 128x128-tile GEMM (for N=384 shapes) ----------------
template<bool GELU>
__launch_bounds__(256, 4)
__global__ void mfma_gemm(const __hip_bfloat16* __restrict__ A,
                          const __hip_bfloat16* __restrict__ Wt,
                          const float* __restrict__ bias,
                          __hip_bfloat16* __restrict__ C,
                          int M, int N, int K, int ldc) {
    __shared__ __align__(16) __hip_bfloat16 As[2][4096];
    __shared__ __align__(16) __hip_bfloat16 Bs[2][4096];

    const int t = threadIdx.x;
    const int lane = t & 63;
    const int wave = t >> 6;
    const int wm0 = (wave >> 1) * 64;
    const int wn0 = (wave & 1) * 64;

    int bx, by;
    xcd_swizzle(bx, by);
    const int row0 = by * 128;
    const int col0 = bx * 128;

    const int rS0 = t >> 2;
    const int rS1 = rS0 + 64;
    const int kcS = (t & 3) ^ ((t >> 3) & 3);

    const __hip_bfloat16* aP0 = A + (size_t)min(row0 + rS0, M - 1) * K;
    const __hip_bfloat16* aP1 = A + (size_t)min(row0 + rS1, M - 1) * K;
    const __hip_bfloat16* bP0 = Wt + (size_t)(col0 + rS0) * K;
    const __hip_bfloat16* bP1 = Wt + (size_t)(col0 + rS1) * K;

    const int off0 = (wave * 64) * 16;
    const int off1 = (256 + wave * 64) * 16;

    f32x4 acc[4][4] = {};

    const int kq = lane >> 4;
    const int lr = lane & 15;
    const int kqx = kq ^ ((lr >> 1) & 3);
    const int rdA = (wm0 + lr) * 32 + kqx * 8;
    const int rdB = (wn0 + lr) * 32 + kqx * 8;

    const int nsteps = K >> 5;

    auto stage = [&](int ks, int buf) {
        int k = ks * 32 + kcS * 8;
        load_lds16(aP0 + k, (char*)As[buf] + off0);
        load_lds16(aP1 + k, (char*)As[buf] + off1);
        load_lds16(bP0 + k, (char*)Bs[buf] + off0);
        load_lds16(bP1 + k, (char*)Bs[buf] + off1);
    };

    stage(0, 0);
    __syncthreads();

    int cur = 0;
    for (int ks = 0; ks < nsteps; ks++) {
        if (ks + 1 < nsteps) stage(ks + 1, cur ^ 1);

        bfrag aF[4], bF[4];
        #pragma unroll
        for (int i = 0; i < 4; i++) {
            aF[i] = *reinterpret_cast<const bfrag*>(&As[cur][rdA + i * 512]);
            bF[i] = *reinterpret_cast<const bfrag*>(&Bs[cur][rdB + i * 512]);
        }
        #pragma unroll
        for (int i = 0; i < 4; i++) {
            #pragma unroll
            for (int j = 0; j < 4; j++) {
                acc[i][j] = __builtin_amdgcn_mfma_f32_16x16x32_bf16(aF[i], bF[j], acc[i][j], 0, 0, 0);
            }
        }
        __syncthreads();
        cur ^= 1;
    }

    #pragma unroll
    for (int i = 0; i < 4; i++) {
        #pragma unroll
        for (int j = 0; j < 4; j++) {
            #pragma unroll
            for (int r = 0; r < 4; r++) {
                int row = row0 + wm0 + i * 16 + kq * 4 + r;
                int col = col0 + wn0 + j * 16 + lr;
                if (row < M) {
                    float v = acc[i][j][r] + bias[col];
                    if constexpr (GELU) v = gelu_f(v);
                    C[(size_t)row * ldc + col] = __float2bfloat16(v);
                }
            }
        }
    }
}

// ---------------- per-chunk segment partial sums (sorted grid_idx, no atomics) ----------------
__global__ void seg_partial(const int* __restrict__ edges, int e0, int e1,
                            const __hip_bfloat16* __restrict__ m3c, float* __restrict__ out) {
    int g = blockIdx.x;
    int l = e0, r = e1;
    while (l < r) { int mid = (l + r) >> 1; if (edges[2 * mid] < g) l = mid + 1; else r = mid; }
    int lo = l;
    r = e1;
    while (l < r) { int mid = (l + r) >> 1; if (edges[2 * mid] <= g) l = mid + 1; else r = mid; }
    int hi = l;
    if (lo >= hi) return;

    int c = threadIdx.x;
    float s0 = 0.f, s1 = 0.f, s2 = 0.f;
    for (int e = lo; e < hi; e++) {
        const __hip_bfloat16* rp = m3c + (size_t)(e - e0) * HID;
        s0 += __bfloat162float(rp[c]);
        s1 += __bfloat162float(rp[c + 128]);
        s2 += __bfloat162float(rp[c + 256]);
    }
    float* orow = out + (size_t)g * HID;
    orow[c] += s0;
    orow[c + 128] += s1;
    orow[c + 256] += s2;
}

// ---------------- final divide by segment count ----------------
__global__ void seg_div(const int* __restrict__ edges, float* __restrict__ out) {
    int g = blockIdx.x;
    int l = 0, r = NEDGE;
    while (l < r) { int mid = (l + r) >> 1; if (edges[2 * mid] < g) l = mid + 1; else r = mid; }
    int lo = l;
    r = NEDGE;
    while (l < r) { int mid = (l + r) >> 1; if (edges[2 * mid] <= g) l = mid + 1; else r = mid; }
    int cnt = l - lo;
    float inv = 1.0f / (float)max(cnt, 1);
    int c = threadIdx.x;
    float* orow = out + (size_t)g * HID;
    orow[c] *= inv;
    orow[c + 128] *= inv;
    orow[c + 256] *= inv;
}

extern "C" void kernel_launch(void* const* d_in, const int* in_sizes, int n_in,
                              void* d_out, int out_size, void* d_ws, size_t ws_size,
                              hipStream_t stream) {
    const float* x        = (const float*)d_in[0];
    const float* mesh_pos = (const float*)d_in[1];
    const float* grid_pos = (const float*)d_in[2];
    const int*   edges    = (const int*)d_in[3];
    const float* w1  = (const float*)d_in[4];
    const float* b1  = (const float*)d_in[5];
    const float* w2  = (const float*)d_in[6];
    const float* b2  = (const float*)d_in[7];
    const float* w3  = (const float*)d_in[8];
    const float* b3  = (const float*)d_in[9];
    const float* wm1 = (const float*)d_in[10];
    const float* bm1 = (const float*)d_in[11];
    const float* wm2 = (const float*)d_in[12];
    const float* bm2 = (const float*)d_in[13];
    const float* wm3 = (const float*)d_in[14];
    const float* bm3 = (const float*)d_in[15];
    float* out = (float*)d_out;

    // ---- workspace layout, ~174 MB total ----
    char* p = (char*)d_ws;
    auto alloc = [&](size_t b) { char* r = p; p += (b + 255) & ~(size_t)255; return r; };
    __hip_bfloat16* wt2   = (__hip_bfloat16*)alloc((size_t)384 * 384 * 2);
    __hip_bfloat16* wt3   = (__hip_bfloat16*)alloc((size_t)384 * 384 * 2);
    __hip_bfloat16* wtm1  = (__hip_bfloat16*)alloc((size_t)768 * 768 * 2);
    __hip_bfloat16* wtm2  = (__hip_bfloat16*)alloc((size_t)768 * 768 * 2);
    __hip_bfloat16* wtm3  = (__hip_bfloat16*)alloc((size_t)384 * 768 * 2);
    __hip_bfloat16* gridf = (__hip_bfloat16*)alloc((size_t)GRIDN * 192 * 2);
    __hip_bfloat16* meshf = (__hip_bfloat16*)alloc((size_t)NMESH * 576 * 2);
    char* U1 = alloc((size_t)CHUNK * 768 * 2);
    char* U2 = alloc((size_t)CHUNK * 768 * 2);
    __hip_bfloat16* h1  = (__hip_bfloat16*)U1;
    __hip_bfloat16* h2  = (__hip_bfloat16*)U2;
    __hip_bfloat16* m1c = (__hip_bfloat16*)U1;
    __hip_bfloat16* m2c = (__hip_bfloat16*)U2;
    __hip_bfloat16* m3c = (__hip_bfloat16*)U1;  // m1c dead once m2c computed

    hipMemsetAsync(out, 0, (size_t)GRIDN * HID * 4, stream);

    transpose_to_bf16<<<(384 * 384 + 255) / 256, 256, 0, stream>>>(w2, wt2, 384, 384);
    transpose_to_bf16<<<(384 * 384 + 255) / 256, 256, 0, stream>>>(w3, wt3, 384, 384);
    transpose_to_bf16<<<(768 * 768 + 255) / 256, 256, 0, stream>>>(wm1, wtm1, 768, 768);
    transpose_to_bf16<<<(768 * 768 + 255) / 256, 256, 0, stream>>>(wm2, wtm2, 768, 768);
    transpose_to_bf16<<<(768 * 384 + 255) / 256, 256, 0, stream>>>(wm3, wtm3, 768, 384);

    embed_kernel<<<(NMESH * 96 + 255) / 256, 256, 0, stream>>>(mesh_pos, meshf, NMESH, 576, 384);
    embed_kernel<<<(GRIDN * 96 + 255) / 256, 256, 0, stream>>>(grid_pos, gridf, GRIDN, 192, 0);

    lin1_kernel<<<(NMESH * HID + 255) / 256, 256, 0, stream>>>(x, w1, b1, h1);

    // h2 = gelu(h1 @ w2 + b2)
    mfma_gemm<true><<<dim3(3, 391), 256, 0, stream>>>(h1, wt2, b2, h2, NMESH, 384, 384, 384);
    // mesh_feat[:, :384] = h2 @ w3 + b3
    mfma_gemm<false><<<dim3(3, 391), 256, 0, stream>>>(h2, wt3, b3, meshf, NMESH, 384, 384, 576);

    for (int c = 0; c < NCHUNK; c++) {
        int e0 = c * CHUNK;
        // m1c = gelu(gather(edges[e0:e0+CHUNK]) @ wm1 + bm1)
        mfma_gemm256<true, true><<<dim3(3, CHUNK / 256), 512, 0, stream>>>(
            nullptr, wtm1, bm1, m1c, CHUNK, 768, 768, 768, edges + 2 * e0, meshf, gridf);
        // m2c = gelu(m1c @ wm2 + bm2)
        mfma_gemm256<false, true><<<dim3(3, CHUNK / 256), 512, 0, stream>>>(
            m1c, wtm2, bm2, m2c, CHUNK, 768, 768, 768, nullptr, nullptr, nullptr);
        // m3c = m2c @ wm3 + bm3   (overwrites m1c region — m1c dead)
        mfma_gemm<false><<<dim3(3, CHUNK / 128), 256, 0, stream>>>(
            m2c, wtm3, bm3, m3c, CHUNK, 384, 768, 384);
        // accumulate segment sums for this chunk
        seg_partial<<<GRIDN, 128, 0, stream>>>(edges, e0, e0 + CHUNK, m3c, out);
    }

    seg_div<<<GRIDN, 128, 0, stream>>>(edges, out);
}

// Round 8
// 1754.237 us; speedup vs baseline: 1.7762x; 1.7762x over previous
//
#include <hip/hip_runtime.h>
#include <hip/hip_bf16.h>

#define NMESH 50000
#define GRIDN 32768
#define NEDGE 131072
#define HID 384

using f32x4 = __attribute__((ext_vector_type(4))) float;
using bfrag = __attribute__((ext_vector_type(8))) short;

__device__ __forceinline__ float gelu_f(float v) {
    return 0.5f * v * (1.0f + erff(v * 0.70710678118654752f));
}

__device__ __forceinline__ void load_lds16(const void* g, void* l) {
    __builtin_amdgcn_global_load_lds(
        (const __attribute__((address_space(1))) void*)g,
        (__attribute__((address_space(3))) void*)l,
        16, 0, 0);
}

// bijective XCD-chunking swizzle (m204)
__device__ __forceinline__ void xcd_swizzle(int& bx, int& by) {
    int gx = gridDim.x;
    int nwg = gx * gridDim.y;
    int l = blockIdx.y * gx + blockIdx.x;
    int q = nwg >> 3, r = nwg & 7;
    int xcd = l & 7, pos = l >> 3;
    int nl = (xcd < r ? xcd * (q + 1) : r * (q + 1) + (xcd - r) * q) + pos;
    by = nl / gx;
    bx = nl - by * gx;
}

// ---------------- weight transpose + bf16 cast: Wt[n*K+k] = W[k*N+n] ----------------
__global__ void transpose_to_bf16(const float* __restrict__ w, __hip_bfloat16* __restrict__ wt,
                                  int K, int N) {
    int idx = blockIdx.x * blockDim.x + threadIdx.x;
    if (idx >= K * N) return;
    int n = idx / K;
    int k = idx - n * K;
    wt[idx] = __float2bfloat16(w[(size_t)k * N + n]);
}

// ---------------- sincos positional embedding ----------------
__global__ void embed_kernel(const float* __restrict__ pos, __hip_bfloat16* __restrict__ outp,
                             int n, int stride, int coloff) {
    int idx = blockIdx.x * blockDim.x + threadIdx.x;
    if (idx >= n * 96) return;
    int nn = idx / 96;
    int rr = idx - nn * 96;
    int d = rr >> 5;
    int k = rr & 31;
    float v = pos[nn * 3 + d];
    float omega = expf(-0.28782313662425575f * (float)k);  // ln(10000)/32
    float a = v * omega;
    __hip_bfloat16* o = outp + (size_t)nn * stride + coloff + d * 64 + k;
    o[0]  = __float2bfloat16(sinf(a));
    o[32] = __float2bfloat16(cosf(a));
}

// ---------------- layer 1: h1 = gelu(x @ w1 + b1), K=16 ----------------
__global__ void lin1_kernel(const float* __restrict__ x, const float* __restrict__ w,
                            const float* __restrict__ b, __hip_bfloat16* __restrict__ h1) {
    int idx = blockIdx.x * blockDim.x + threadIdx.x;
    if (idx >= NMESH * HID) return;
    int m = idx / HID;
    int n = idx - m * HID;
    float acc = b[n];
    const float* xr = x + m * 16;
    #pragma unroll
    for (int k = 0; k < 16; k++) acc = fmaf(xr[k], w[k * HID + n], acc);
    h1[idx] = __float2bfloat16(gelu_f(acc));
}

// ======================================================================
// 256x256-tile bf16 MFMA GEMM: 8 waves (2Mx4N), per-wave 128x64 out,
// BK=64 -> 64 MFMA/wave per barrier interval. LDS 128KB dbuf, 1 block/CU,
// __launch_bounds__(512,2) -> 256-VGPR budget (acc 128 + frags 48: fits,
// NO spill -- round 7's (512,4) capped at 128 and spilled acc to scratch).
// Pre-swizzled global_load_lds: physical slot p holds (row=p>>3,
// kc=(p&7)^(row&7)); fragment reads use chunk=(kk*4+kq)^(lr&7): every
// 8-lane group hits 8 distinct 16B-slots mod 8 = conflict-free b128.
// ======================================================================
template<bool GATHER, bool GELU>
__launch_bounds__(512, 2)
__global__ void mfma_gemm256(const __hip_bfloat16* __restrict__ A,
                             const __hip_bfloat16* __restrict__ Wt,
                             const float* __restrict__ bias,
                             __hip_bfloat16* __restrict__ C,
                             int M, int N, int K, int ldc,
                             const int* __restrict__ edges,
                             const __hip_bfloat16* __restrict__ meshf,
                             const __hip_bfloat16* __restrict__ gridf) {
    __shared__ __align__(16) __hip_bfloat16 As[2][16384];  // 256 rows x 64 k
    __shared__ __align__(16) __hip_bfloat16 Bs[2][16384];

    const int t = threadIdx.x;       // 0..511
    const int lane = t & 63;
    const int wave = t >> 6;         // 0..7
    const int wm0 = (wave >> 2) * 128;   // 2 row-groups
    const int wn0 = (wave & 3) * 64;     // 4 col-groups

    int bx, by;
    xcd_swizzle(bx, by);
    const int row0 = by * 256;
    const int col0 = bx * 256;

    // staging: thread t covers physical slots p = t + j*512, j=0..3.
    // row_j = (t>>3) + j*64 ; logical kc = (t&7)^((t>>3)&7), j-invariant.
    const int rBase = t >> 3;
    const int kcS = (t & 7) ^ ((t >> 3) & 7);

    const __hip_bfloat16 *aP[4], *aQ[4], *bP[4];
    #pragma unroll
    for (int j = 0; j < 4; j++) {
        int rw = rBase + j * 64;
        if constexpr (GATHER) {
            int e = min(row0 + rw, M - 1);
            aP[j] = meshf + (size_t)edges[2 * e + 1] * 576;   // k in [0,576)
            aQ[j] = gridf + (size_t)edges[2 * e + 0] * 192;   // k in [576,768)
        } else {
            aP[j] = A + (size_t)min(row0 + rw, M - 1) * K;
            aQ[j] = nullptr;
        }
        bP[j] = Wt + (size_t)(col0 + rw) * K;
    }

    f32x4 acc[8][4] = {};

    const int kq = lane >> 4;
    const int lr = lane & 15;
    const int xk = lr & 7;

    const int nsteps = K >> 6;   // BK=64

    auto stage = [&](int ks, int buf) {
        int k = ks * 64 + kcS * 8;
        #pragma unroll
        for (int j = 0; j < 4; j++) {
            const __hip_bfloat16* sa;
            if constexpr (GATHER) {
                sa = (k < 576) ? (aP[j] + k) : (aQ[j] + (k - 576));
            } else {
                sa = aP[j] + k;
            }
            load_lds16(sa, (char*)As[buf] + (wave * 64 + j * 512) * 16);
            load_lds16(bP[j] + k, (char*)Bs[buf] + (wave * 64 + j * 512) * 16);
        }
    };

    stage(0, 0);
    __syncthreads();

    int cur = 0;
    for (int ks = 0; ks < nsteps; ks++) {
        if (ks + 1 < nsteps) stage(ks + 1, cur ^ 1);  // issue next-tile loads first

        #pragma unroll
        for (int kk = 0; kk < 2; kk++) {
            const int ca = (((kk << 2) | kq) ^ xk) << 3;   // chunk byte-ish (elem) offset
            bfrag aF[8], bF[4];
            #pragma unroll
            for (int i = 0; i < 8; i++)
                aF[i] = *reinterpret_cast<const bfrag*>(&As[cur][(wm0 + i * 16 + lr) * 64 + ca]);
            #pragma unroll
            for (int j = 0; j < 4; j++)
                bF[j] = *reinterpret_cast<const bfrag*>(&Bs[cur][(wn0 + j * 16 + lr) * 64 + ca]);
            #pragma unroll
            for (int i = 0; i < 8; i++) {
                #pragma unroll
                for (int j = 0; j < 4; j++) {
                    acc[i][j] = __builtin_amdgcn_mfma_f32_16x16x32_bf16(aF[i], bF[j], acc[i][j], 0, 0, 0);
                }
            }
        }
        __syncthreads();
        cur ^= 1;
    }

    // C/D layout: col = lane&15, row = (lane>>4)*4 + reg
    #pragma unroll
    for (int i = 0; i < 8; i++) {
        #pragma unroll
        for (int j = 0; j < 4; j++) {
            #pragma unroll
            for (int r = 0; r < 4; r++) {
                int row = row0 + wm0 + i * 16 + kq * 4 + r;
                int col = col0 + wn0 + j * 16 + lr;
                if (row < M) {
                    float v = acc[i][j][r] + bias[col];
                    if constexpr (GELU) v = gelu_f(v);
                    C[(size_t)row * ldc + col] = __float2bfloat16(v);
                }
            }
        }
    }
}

// ---------------- 128x128-tile GEMM (N=384 shapes; proven, 0 conflicts) ----------------
template<bool GELU>
__launch_bounds__(256, 4)
__global__ void mfma_gemm(const __hip_bfloat16* __restrict__ A,
                          const __hip_bfloat16* __restrict__ Wt,
                          const float* __restrict__ bias,
                          __hip_bfloat16* __restrict__ C,
                          int M, int N, int K, int ldc) {
    __shared__ __align__(16) __hip_bfloat16 As[2][4096];
    __shared__ __align__(16) __hip_bfloat16 Bs[2][4096];

    const int t = threadIdx.x;
    const int lane = t & 63;
    const int wave = t >> 6;
    const int wm0 = (wave >> 1) * 64;
    const int wn0 = (wave & 1) * 64;

    int bx, by;
    xcd_swizzle(bx, by);
    const int row0 = by * 128;
    const int col0 = bx * 128;

    const int rS0 = t >> 2;
    const int rS1 = rS0 + 64;
    const int kcS = (t & 3) ^ ((t >> 3) & 3);

    const __hip_bfloat16* aP0 = A + (size_t)min(row0 + rS0, M - 1) * K;
    const __hip_bfloat16* aP1 = A + (size_t)min(row0 + rS1, M - 1) * K;
    const __hip_bfloat16* bP0 = Wt + (size_t)(col0 + rS0) * K;
    const __hip_bfloat16* bP1 = Wt + (size_t)(col0 + rS1) * K;

    const int off0 = (wave * 64) * 16;
    const int off1 = (256 + wave * 64) * 16;

    f32x4 acc[4][4] = {};

    const int kq = lane >> 4;
    const int lr = lane & 15;
    const int kqx = kq ^ ((lr >> 1) & 3);
    const int rdA = (wm0 + lr) * 32 + kqx * 8;
    const int rdB = (wn0 + lr) * 32 + kqx * 8;

    const int nsteps = K >> 5;

    auto stage = [&](int ks, int buf) {
        int k = ks * 32 + kcS * 8;
        load_lds16(aP0 + k, (char*)As[buf] + off0);
        load_lds16(aP1 + k, (char*)As[buf] + off1);
        load_lds16(bP0 + k, (char*)Bs[buf] + off0);
        load_lds16(bP1 + k, (char*)Bs[buf] + off1);
    };

    stage(0, 0);
    __syncthreads();

    int cur = 0;
    for (int ks = 0; ks < nsteps; ks++) {
        if (ks + 1 < nsteps) stage(ks + 1, cur ^ 1);

        bfrag aF[4], bF[4];
        #pragma unroll
        for (int i = 0; i < 4; i++) {
            aF[i] = *reinterpret_cast<const bfrag*>(&As[cur][rdA + i * 512]);
            bF[i] = *reinterpret_cast<const bfrag*>(&Bs[cur][rdB + i * 512]);
        }
        #pragma unroll
        for (int i = 0; i < 4; i++) {
            #pragma unroll
            for (int j = 0; j < 4; j++) {
                acc[i][j] = __builtin_amdgcn_mfma_f32_16x16x32_bf16(aF[i], bF[j], acc[i][j], 0, 0, 0);
            }
        }
        __syncthreads();
        cur ^= 1;
    }

    #pragma unroll
    for (int i = 0; i < 4; i++) {
        #pragma unroll
        for (int j = 0; j < 4; j++) {
            #pragma unroll
            for (int r = 0; r < 4; r++) {
                int row = row0 + wm0 + i * 16 + kq * 4 + r;
                int col = col0 + wn0 + j * 16 + lr;
                if (row < M) {
                    float v = acc[i][j][r] + bias[col];
                    if constexpr (GELU) v = gelu_f(v);
                    C[(size_t)row * ldc + col] = __float2bfloat16(v);
                }
            }
        }
    }
}

// ---------------- per-chunk segment partial sums (sorted grid_idx, no atomics) ----------------
__global__ void seg_partial(const int* __restrict__ edges, int e0, int e1,
                            const __hip_bfloat16* __restrict__ m3c, float* __restrict__ out) {
    int g = blockIdx.x;
    int l = e0, r = e1;
    while (l < r) { int mid = (l + r) >> 1; if (edges[2 * mid] < g) l = mid + 1; else r = mid; }
    int lo = l;
    r = e1;
    while (l < r) { int mid = (l + r) >> 1; if (edges[2 * mid] <= g) l = mid + 1; else r = mid; }
    int hi = l;
    if (lo >= hi) return;

    int c = threadIdx.x;
    float s0 = 0.f, s1 = 0.f, s2 = 0.f;
    for (int e = lo; e < hi; e++) {
        const __hip_bfloat16* rp = m3c + (size_t)(e - e0) * HID;
        s0 += __bfloat162float(rp[c]);
        s1 += __bfloat162float(rp[c + 128]);
        s2 += __bfloat162float(rp[c + 256]);
    }
    float* orow = out + (size_t)g * HID;
    orow[c] += s0;
    orow[c + 128] += s1;
    orow[c + 256] += s2;
}

// ---------------- final divide by segment count ----------------
__global__ void seg_div(const int* __restrict__ edges, float* __restrict__ out) {
    int g = blockIdx.x;
    int l = 0, r = NEDGE;
    while (l < r) { int mid = (l + r) >> 1; if (edges[2 * mid] < g) l = mid + 1; else r = mid; }
    int lo = l;
    r = NEDGE;
    while (l < r) { int mid = (l + r) >> 1; if (edges[2 * mid] <= g) l = mid + 1; else r = mid; }
    int cnt = l - lo;
    float inv = 1.0f / (float)max(cnt, 1);
    int c = threadIdx.x;
    float* orow = out + (size_t)g * HID;
    orow[c] *= inv;
    orow[c + 128] *= inv;
    orow[c + 256] *= inv;
}

extern "C" void kernel_launch(void* const* d_in, const int* in_sizes, int n_in,
                              void* d_out, int out_size, void* d_ws, size_t ws_size,
                              hipStream_t stream) {
    const float* x        = (const float*)d_in[0];
    const float* mesh_pos = (const float*)d_in[1];
    const float* grid_pos = (const float*)d_in[2];
    const int*   edges    = (const int*)d_in[3];
    const float* w1  = (const float*)d_in[4];
    const float* b1  = (const float*)d_in[5];
    const float* w2  = (const float*)d_in[6];
    const float* b2  = (const float*)d_in[7];
    const float* w3  = (const float*)d_in[8];
    const float* b3  = (const float*)d_in[9];
    const float* wm1 = (const float*)d_in[10];
    const float* bm1 = (const float*)d_in[11];
    const float* wm2 = (const float*)d_in[12];
    const float* bm2 = (const float*)d_in[13];
    const float* wm3 = (const float*)d_in[14];
    const float* bm3 = (const float*)d_in[15];
    float* out = (float*)d_out;

    // ---- chunk size: 65536 (grid = 3x256 blocks = 3 full CU-waves at
    // 1 block/CU) if workspace allows (~276 MB), else proven 32768 (~174 MB).
    auto rnd = [](size_t b) { return (b + 255) & ~(size_t)255; };
    size_t fixedB = rnd((size_t)384 * 384 * 2) * 2 + rnd((size_t)768 * 768 * 2) * 2 +
                    rnd((size_t)768 * 384 * 2) + rnd((size_t)GRIDN * 192 * 2) +
                    rnd((size_t)NMESH * 576 * 2);
    const int CH = (ws_size >= fixedB + 2 * rnd((size_t)65536 * 768 * 2) + 65536) ? 65536 : 32768;
    const int NCH = NEDGE / CH;

    char* p = (char*)d_ws;
    auto alloc = [&](size_t b) { char* r = p; p += (b + 255) & ~(size_t)255; return r; };
    __hip_bfloat16* wt2   = (__hip_bfloat16*)alloc((size_t)384 * 384 * 2);
    __hip_bfloat16* wt3   = (__hip_bfloat16*)alloc((size_t)384 * 384 * 2);
    __hip_bfloat16* wtm1  = (__hip_bfloat16*)alloc((size_t)768 * 768 * 2);
    __hip_bfloat16* wtm2  = (__hip_bfloat16*)alloc((size_t)768 * 768 * 2);
    __hip_bfloat16* wtm3  = (__hip_bfloat16*)alloc((size_t)384 * 768 * 2);
    __hip_bfloat16* gridf = (__hip_bfloat16*)alloc((size_t)GRIDN * 192 * 2);
    __hip_bfloat16* meshf = (__hip_bfloat16*)alloc((size_t)NMESH * 576 * 2);
    char* U1 = alloc((size_t)CH * 768 * 2);
    char* U2 = alloc((size_t)CH * 768 * 2);
    __hip_bfloat16* h1  = (__hip_bfloat16*)U1;   // 38.4 MB, fits (CH>=32768)
    __hip_bfloat16* h2  = (__hip_bfloat16*)U2;
    __hip_bfloat16* m1c = (__hip_bfloat16*)U1;
    __hip_bfloat16* m2c = (__hip_bfloat16*)U2;
    __hip_bfloat16* m3c = (__hip_bfloat16*)U1;   // m1c dead once m2c computed

    hipMemsetAsync(out, 0, (size_t)GRIDN * HID * 4, stream);

    transpose_to_bf16<<<(384 * 384 + 255) / 256, 256, 0, stream>>>(w2, wt2, 384, 384);
    transpose_to_bf16<<<(384 * 384 + 255) / 256, 256, 0, stream>>>(w3, wt3, 384, 384);
    transpose_to_bf16<<<(768 * 768 + 255) / 256, 256, 0, stream>>>(wm1, wtm1, 768, 768);
    transpose_to_bf16<<<(768 * 768 + 255) / 256, 256, 0, stream>>>(wm2, wtm2, 768, 768);
    transpose_to_bf16<<<(768 * 384 + 255) / 256, 256, 0, stream>>>(wm3, wtm3, 768, 384);

    embed_kernel<<<(NMESH * 96 + 255) / 256, 256, 0, stream>>>(mesh_pos, meshf, NMESH, 576, 384);
    embed_kernel<<<(GRIDN * 96 + 255) / 256, 256, 0, stream>>>(grid_pos, gridf, GRIDN, 192, 0);

    lin1_kernel<<<(NMESH * HID + 255) / 256, 256, 0, stream>>>(x, w1, b1, h1);

    // h2 = gelu(h1 @ w2 + b2)
    mfma_gemm<true><<<dim3(3, 391), 256, 0, stream>>>(h1, wt2, b2, h2, NMESH, 384, 384, 384);
    // mesh_feat[:, :384] = h2 @ w3 + b3
    mfma_gemm<false><<<dim3(3, 391), 256, 0, stream>>>(h2, wt3, b3, meshf, NMESH, 384, 384, 576);

    for (int c = 0; c < NCH; c++) {
        int e0 = c * CH;
        // m1c = gelu(gather(edges[e0:e0+CH]) @ wm1 + bm1)
        mfma_gemm256<true, true><<<dim3(3, CH / 256), 512, 0, stream>>>(
            nullptr, wtm1, bm1, m1c, CH, 768, 768, 768, edges + 2 * e0, meshf, gridf);
        // m2c = gelu(m1c @ wm2 + bm2)
        mfma_gemm256<false, true><<<dim3(3, CH / 256), 512, 0, stream>>>(
            m1c, wtm2, bm2, m2c, CH, 768, 768, 768, nullptr, nullptr, nullptr);
        // m3c = m2c @ wm3 + bm3   (overwrites m1c region — m1c dead)
        mfma_gemm<false><<<dim3(3, CH / 128), 256, 0, stream>>>(
            m2c, wtm3, bm3, m3c, CH, 384, 768, 384);
        // accumulate segment sums for this chunk
        seg_partial<<<GRIDN, 128, 0, stream>>>(edges, e0, e0 + CH, m3c, out);
    }

    seg_div<<<GRIDN, 128, 0, stream>>>(edges, out);
}

// Round 9
// 1445.802 us; speedup vs baseline: 2.1552x; 1.2133x over previous
//
#include <hip/hip_runtime.h>
#include <hip/hip_bf16.h>

#define NMESH 50000
#define GRIDN 32768
#define NEDGE 131072
#define HID 384
#define CHUNK 32768
#define NCHUNK 4

using f32x4 = __attribute__((ext_vector_type(4))) float;
using bfrag = __attribute__((ext_vector_type(8))) short;

__device__ __forceinline__ float gelu_f(float v) {
    return 0.5f * v * (1.0f + erff(v * 0.70710678118654752f));
}

__device__ __forceinline__ void load_lds16(const void* g, void* l) {
    __builtin_amdgcn_global_load_lds(
        (const __attribute__((address_space(1))) void*)g,
        (__attribute__((address_space(3))) void*)l,
        16, 0, 0);
}

// bijective XCD-chunking swizzle (m204)
__device__ __forceinline__ void xcd_swizzle(int& bx, int& by) {
    int gx = gridDim.x;
    int nwg = gx * gridDim.y;
    int l = blockIdx.y * gx + blockIdx.x;
    int q = nwg >> 3, r = nwg & 7;
    int xcd = l & 7, pos = l >> 3;
    int nl = (xcd < r ? xcd * (q + 1) : r * (q + 1) + (xcd - r) * q) + pos;
    by = nl / gx;
    bx = nl - by * gx;
}

// ---------------- weight transpose + bf16 cast: Wt[n*K+k] = W[k*N+n] ----------------
__global__ void transpose_to_bf16(const float* __restrict__ w, __hip_bfloat16* __restrict__ wt,
                                  int K, int N) {
    int idx = blockIdx.x * blockDim.x + threadIdx.x;
    if (idx >= K * N) return;
    int n = idx / K;
    int k = idx - n * K;
    wt[idx] = __float2bfloat16(w[(size_t)k * N + n]);
}

// ---------------- sincos positional embedding ----------------
__global__ void embed_kernel(const float* __restrict__ pos, __hip_bfloat16* __restrict__ outp,
                             int n, int stride, int coloff) {
    int idx = blockIdx.x * blockDim.x + threadIdx.x;
    if (idx >= n * 96) return;
    int nn = idx / 96;
    int rr = idx - nn * 96;
    int d = rr >> 5;
    int k = rr & 31;
    float v = pos[nn * 3 + d];
    float omega = expf(-0.28782313662425575f * (float)k);  // ln(10000)/32
    float a = v * omega;
    __hip_bfloat16* o = outp + (size_t)nn * stride + coloff + d * 64 + k;
    o[0]  = __float2bfloat16(sinf(a));
    o[32] = __float2bfloat16(cosf(a));
}

// ---------------- layer 1: h1 = gelu(x @ w1 + b1), K=16 ----------------
__global__ void lin1_kernel(const float* __restrict__ x, const float* __restrict__ w,
                            const float* __restrict__ b, __hip_bfloat16* __restrict__ h1) {
    int idx = blockIdx.x * blockDim.x + threadIdx.x;
    if (idx >= NMESH * HID) return;
    int m = idx / HID;
    int n = idx - m * HID;
    float acc = b[n];
    const float* xr = x + m * 16;
    #pragma unroll
    for (int k = 0; k < 16; k++) acc = fmaf(xr[k], w[k * HID + n], acc);
    h1[idx] = __float2bfloat16(gelu_f(acc));
}

// ======================================================================
// 128x128-tile bf16 MFMA GEMM, BK=32, 4 waves (2x2), 16x16x32 MFMA.
// COUNTED-VMCNT PIPELINE (T4): 4 LDS buffers, prefetch depth 3.
//   per step ks: s_waitcnt vmcnt(8)  -> tile ks landed; ks+1,ks+2 stay
//                IN FLIGHT across the raw s_barrier (no compiler drain);
//                raw barrier          -> all waves done reading tile ks-1
//                stage(ks+3)          -> overwrites ks-1's buffer (safe)
//                ds_read + MFMA on buf[ks&3]
// Pre-swizzled global_load_lds (proven, 0 bank conflicts): physical slot
// p holds (row=p>>2, kc=(p&3)^((p>>3)&3)); fragment reads at
// kqx = kq^((lr>>1)&3). LDS 64KB -> 2 blocks/CU for inter-block overlap.
// ======================================================================
template<bool GATHER, bool GELU>
__launch_bounds__(256, 4)
__global__ void mfma_gemm(const __hip_bfloat16* __restrict__ A,
                          const __hip_bfloat16* __restrict__ Wt,
                          const float* __restrict__ bias,
                          __hip_bfloat16* __restrict__ C,
                          int M, int N, int K, int ldc,
                          const int* __restrict__ edges,
                          const __hip_bfloat16* __restrict__ meshf,
                          const __hip_bfloat16* __restrict__ gridf) {
    __shared__ __align__(16) __hip_bfloat16 As[4][4096];
    __shared__ __align__(16) __hip_bfloat16 Bs[4][4096];

    const int t = threadIdx.x;
    const int lane = t & 63;
    const int wave = t >> 6;
    const int wm0 = (wave >> 1) * 64;
    const int wn0 = (wave & 1) * 64;

    int bx, by;
    xcd_swizzle(bx, by);
    const int row0 = by * 128;
    const int col0 = bx * 128;

    // staging: thread t covers physical slots t (rows 0..63) and t+256 (rows 64..127)
    const int rS0 = t >> 2;
    const int rS1 = rS0 + 64;
    const int kcS = (t & 3) ^ ((t >> 3) & 3);   // logical k-chunk

    const __hip_bfloat16 *aP0, *aP1, *aQ0 = nullptr, *aQ1 = nullptr;
    if constexpr (GATHER) {
        int e0 = min(row0 + rS0, M - 1);
        int e1 = min(row0 + rS1, M - 1);
        aP0 = meshf + (size_t)edges[2 * e0 + 1] * 576;
        aQ0 = gridf + (size_t)edges[2 * e0 + 0] * 192;
        aP1 = meshf + (size_t)edges[2 * e1 + 1] * 576;
        aQ1 = gridf + (size_t)edges[2 * e1 + 0] * 192;
    } else {
        aP0 = A + (size_t)min(row0 + rS0, M - 1) * K;
        aP1 = A + (size_t)min(row0 + rS1, M - 1) * K;
    }
    const __hip_bfloat16* bP0 = Wt + (size_t)(col0 + rS0) * K;
    const __hip_bfloat16* bP1 = Wt + (size_t)(col0 + rS1) * K;

    // wave-uniform LDS dest byte bases within a buffer (HW adds lane*16)
    const int off0 = (wave * 64) * 16;
    const int off1 = (256 + wave * 64) * 16;

    f32x4 acc[4][4] = {};

    const int kq = lane >> 4;
    const int lr = lane & 15;
    const int kqx = kq ^ ((lr >> 1) & 3);   // swizzled k-chunk for fragment reads
    const int rdA = (wm0 + lr) * 32 + kqx * 8;
    const int rdB = (wn0 + lr) * 32 + kqx * 8;

    const int nsteps = K >> 5;   // >= 12 for all our shapes

    auto stage = [&](int ks, int buf) {
        int k = ks * 32 + kcS * 8;
        const __hip_bfloat16 *sa0, *sa1;
        if constexpr (GATHER) {
            sa0 = (k < 576) ? (aP0 + k) : (aQ0 + (k - 576));
            sa1 = (k < 576) ? (aP1 + k) : (aQ1 + (k - 576));
        } else {
            sa0 = aP0 + k;
            sa1 = aP1 + k;
        }
        load_lds16(sa0, (char*)As[buf] + off0);
        load_lds16(sa1, (char*)As[buf] + off1);
        load_lds16(bP0 + k, (char*)Bs[buf] + off0);
        load_lds16(bP1 + k, (char*)Bs[buf] + off1);
    };

    // prologue: stage tiles 0,1,2 (12 loads in flight)
    stage(0, 0);
    stage(1, 1);
    stage(2, 2);

    for (int ks = 0; ks < nsteps; ks++) {
        // counted wait: retire tile ks; keep ks+1, ks+2 in flight
        if (ks + 2 < nsteps) {
            asm volatile("s_waitcnt vmcnt(8)" ::: "memory");
        } else if (ks + 1 < nsteps) {
            asm volatile("s_waitcnt vmcnt(4)" ::: "memory");
        } else {
            asm volatile("s_waitcnt vmcnt(0)" ::: "memory");
        }
        __builtin_amdgcn_s_barrier();   // raw barrier: no compiler vmcnt(0) drain
        if (ks + 3 < nsteps) stage(ks + 3, (ks + 3) & 3);

        const int cur = ks & 3;
        bfrag aF[4], bF[4];
        #pragma unroll
        for (int i = 0; i < 4; i++) {
            aF[i] = *reinterpret_cast<const bfrag*>(&As[cur][rdA + i * 512]);
            bF[i] = *reinterpret_cast<const bfrag*>(&Bs[cur][rdB + i * 512]);
        }
        asm volatile("s_waitcnt lgkmcnt(0)" ::: "memory");
        __builtin_amdgcn_sched_barrier(0);   // rule #18: keep MFMA below the wait
        __builtin_amdgcn_s_setprio(1);
        #pragma unroll
        for (int i = 0; i < 4; i++) {
            #pragma unroll
            for (int j = 0; j < 4; j++) {
                acc[i][j] = __builtin_amdgcn_mfma_f32_16x16x32_bf16(aF[i], bF[j], acc[i][j], 0, 0, 0);
            }
        }
        __builtin_amdgcn_s_setprio(0);
    }

    // C/D layout: col = lane&15, row = (lane>>4)*4 + reg
    #pragma unroll
    for (int i = 0; i < 4; i++) {
        #pragma unroll
        for (int j = 0; j < 4; j++) {
            #pragma unroll
            for (int r = 0; r < 4; r++) {
                int row = row0 + wm0 + i * 16 + kq * 4 + r;
                int col = col0 + wn0 + j * 16 + lr;
                if (row < M) {
                    float v = acc[i][j][r] + bias[col];
                    if constexpr (GELU) v = gelu_f(v);
                    C[(size_t)row * ldc + col] = __float2bfloat16(v);
                }
            }
        }
    }
}

// ---------------- per-chunk segment partial sums (sorted grid_idx, no atomics) ----------------
__global__ void seg_partial(const int* __restrict__ edges, int e0, int e1,
                            const __hip_bfloat16* __restrict__ m3c, float* __restrict__ out) {
    int g = blockIdx.x;
    int l = e0, r = e1;
    while (l < r) { int mid = (l + r) >> 1; if (edges[2 * mid] < g) l = mid + 1; else r = mid; }
    int lo = l;
    r = e1;
    while (l < r) { int mid = (l + r) >> 1; if (edges[2 * mid] <= g) l = mid + 1; else r = mid; }
    int hi = l;
    if (lo >= hi) return;

    int c = threadIdx.x;
    float s0 = 0.f, s1 = 0.f, s2 = 0.f;
    for (int e = lo; e < hi; e++) {
        const __hip_bfloat16* rp = m3c + (size_t)(e - e0) * HID;
        s0 += __bfloat162float(rp[c]);
        s1 += __bfloat162float(rp[c + 128]);
        s2 += __bfloat162float(rp[c + 256]);
    }
    float* orow = out + (size_t)g * HID;
    orow[c] += s0;
    orow[c + 128] += s1;
    orow[c + 256] += s2;
}

// ---------------- final divide by segment count ----------------
__global__ void seg_div(const int* __restrict__ edges, float* __restrict__ out) {
    int g = blockIdx.x;
    int l = 0, r = NEDGE;
    while (l < r) { int mid = (l + r) >> 1; if (edges[2 * mid] < g) l = mid + 1; else r = mid; }
    int lo = l;
    r = NEDGE;
    while (l < r) { int mid = (l + r) >> 1; if (edges[2 * mid] <= g) l = mid + 1; else r = mid; }
    int cnt = l - lo;
    float inv = 1.0f / (float)max(cnt, 1);
    int c = threadIdx.x;
    float* orow = out + (size_t)g * HID;
    orow[c] *= inv;
    orow[c + 128] *= inv;
    orow[c + 256] *= inv;
}

extern "C" void kernel_launch(void* const* d_in, const int* in_sizes, int n_in,
                              void* d_out, int out_size, void* d_ws, size_t ws_size,
                              hipStream_t stream) {
    const float* x        = (const float*)d_in[0];
    const float* mesh_pos = (const float*)d_in[1];
    const float* grid_pos = (const float*)d_in[2];
    const int*   edges    = (const int*)d_in[3];
    const float* w1  = (const float*)d_in[4];
    const float* b1  = (const float*)d_in[5];
    const float* w2  = (const float*)d_in[6];
    const float* b2  = (const float*)d_in[7];
    const float* w3  = (const float*)d_in[8];
    const float* b3  = (const float*)d_in[9];
    const float* wm1 = (const float*)d_in[10];
    const float* bm1 = (const float*)d_in[11];
    const float* wm2 = (const float*)d_in[12];
    const float* bm2 = (const float*)d_in[13];
    const float* wm3 = (const float*)d_in[14];
    const float* bm3 = (const float*)d_in[15];
    float* out = (float*)d_out;

    // ---- workspace layout, ~174 MB total (proven) ----
    char* p = (char*)d_ws;
    auto alloc = [&](size_t b) { char* r = p; p += (b + 255) & ~(size_t)255; return r; };
    __hip_bfloat16* wt2   = (__hip_bfloat16*)alloc((size_t)384 * 384 * 2);
    __hip_bfloat16* wt3   = (__hip_bfloat16*)alloc((size_t)384 * 384 * 2);
    __hip_bfloat16* wtm1  = (__hip_bfloat16*)alloc((size_t)768 * 768 * 2);
    __hip_bfloat16* wtm2  = (__hip_bfloat16*)alloc((size_t)768 * 768 * 2);
    __hip_bfloat16* wtm3  = (__hip_bfloat16*)alloc((size_t)384 * 768 * 2);
    __hip_bfloat16* gridf = (__hip_bfloat16*)alloc((size_t)GRIDN * 192 * 2);
    __hip_bfloat16* meshf = (__hip_bfloat16*)alloc((size_t)NMESH * 576 * 2);
    char* U1 = alloc((size_t)CHUNK * 768 * 2);
    char* U2 = alloc((size_t)CHUNK * 768 * 2);
    __hip_bfloat16* h1  = (__hip_bfloat16*)U1;
    __hip_bfloat16* h2  = (__hip_bfloat16*)U2;
    __hip_bfloat16* m1c = (__hip_bfloat16*)U1;
    __hip_bfloat16* m2c = (__hip_bfloat16*)U2;
    __hip_bfloat16* m3c = (__hip_bfloat16*)U1;  // m1c dead once m2c computed

    hipMemsetAsync(out, 0, (size_t)GRIDN * HID * 4, stream);

    transpose_to_bf16<<<(384 * 384 + 255) / 256, 256, 0, stream>>>(w2, wt2, 384, 384);
    transpose_to_bf16<<<(384 * 384 + 255) / 256, 256, 0, stream>>>(w3, wt3, 384, 384);
    transpose_to_bf16<<<(768 * 768 + 255) / 256, 256, 0, stream>>>(wm1, wtm1, 768, 768);
    transpose_to_bf16<<<(768 * 768 + 255) / 256, 256, 0, stream>>>(wm2, wtm2, 768, 768);
    transpose_to_bf16<<<(768 * 384 + 255) / 256, 256, 0, stream>>>(wm3, wtm3, 768, 384);

    embed_kernel<<<(NMESH * 96 + 255) / 256, 256, 0, stream>>>(mesh_pos, meshf, NMESH, 576, 384);
    embed_kernel<<<(GRIDN * 96 + 255) / 256, 256, 0, stream>>>(grid_pos, gridf, GRIDN, 192, 0);

    lin1_kernel<<<(NMESH * HID + 255) / 256, 256, 0, stream>>>(x, w1, b1, h1);

    // h2 = gelu(h1 @ w2 + b2)
    mfma_gemm<false, true><<<dim3(3, 391), 256, 0, stream>>>(
        h1, wt2, b2, h2, NMESH, 384, 384, 384, nullptr, nullptr, nullptr);
    // mesh_feat[:, :384] = h2 @ w3 + b3
    mfma_gemm<false, false><<<dim3(3, 391), 256, 0, stream>>>(
        h2, wt3, b3, meshf, NMESH, 384, 384, 576, nullptr, nullptr, nullptr);

    for (int c = 0; c < NCHUNK; c++) {
        int e0 = c * CHUNK;
        // m1c = gelu(gather(edges[e0:e0+CHUNK]) @ wm1 + bm1)
        mfma_gemm<true, true><<<dim3(6, CHUNK / 128), 256, 0, stream>>>(
            nullptr, wtm1, bm1, m1c, CHUNK, 768, 768, 768, edges + 2 * e0, meshf, gridf);
        // m2c = gelu(m1c @ wm2 + bm2)
        mfma_gemm<false, true><<<dim3(6, CHUNK / 128), 256, 0, stream>>>(
            m1c, wtm2, bm2, m2c, CHUNK, 768, 768, 768, nullptr, nullptr, nullptr);
        // m3c = m2c @ wm3 + bm3   (overwrites m1c region — m1c dead)
        mfma_gemm<false, false><<<dim3(3, CHUNK / 128), 256, 0, stream>>>(
            m2c, wtm3, bm3, m3c, CHUNK, 384, 768, 384, nullptr, nullptr, nullptr);
        // accumulate segment sums for this chunk
        seg_partial<<<GRIDN, 128, 0, stream>>>(edges, e0, e0 + CHUNK, m3c, out);
    }

    seg_div<<<GRIDN, 128, 0, stream>>>(edges, out);
}

// Round 10
// 1205.539 us; speedup vs baseline: 2.5847x; 1.1993x over previous
//
#include <hip/hip_runtime.h>
#include <hip/hip_bf16.h>

#define NMESH 50000
#define GRIDN 32768
#define NEDGE 131072
#define HID 384
#define CHUNK 32768
#define NCHUNK 4

using f32x4 = __attribute__((ext_vector_type(4))) float;
using bfrag = __attribute__((ext_vector_type(8))) short;

__device__ __forceinline__ float gelu_f(float v) {
    return 0.5f * v * (1.0f + erff(v * 0.70710678118654752f));
}

__device__ __forceinline__ void load_lds16(const void* g, void* l) {
    __builtin_amdgcn_global_load_lds(
        (const __attribute__((address_space(1))) void*)g,
        (__attribute__((address_space(3))) void*)l,
        16, 0, 0);
}

// bijective XCD-chunking swizzle (m204)
__device__ __forceinline__ void xcd_swizzle(int& bx, int& by) {
    int gx = gridDim.x;
    int nwg = gx * gridDim.y;
    int l = blockIdx.y * gx + blockIdx.x;
    int q = nwg >> 3, r = nwg & 7;
    int xcd = l & 7, pos = l >> 3;
    int nl = (xcd < r ? xcd * (q + 1) : r * (q + 1) + (xcd - r) * q) + pos;
    by = nl / gx;
    bx = nl - by * gx;
}

// ---------------- weight transpose + bf16 cast: wt[n*K+k] = w[(k0+k)*N+n] ----------------
__global__ void transpose_to_bf16(const float* __restrict__ w, __hip_bfloat16* __restrict__ wt,
                                  int K, int N, int k0) {
    int idx = blockIdx.x * blockDim.x + threadIdx.x;
    if (idx >= K * N) return;
    int n = idx / K;
    int k = idx - n * K;
    wt[idx] = __float2bfloat16(w[(size_t)(k0 + k) * N + n]);
}

// ---------------- sincos positional embedding ----------------
__global__ void embed_kernel(const float* __restrict__ pos, __hip_bfloat16* __restrict__ outp,
                             int n, int stride, int coloff) {
    int idx = blockIdx.x * blockDim.x + threadIdx.x;
    if (idx >= n * 96) return;
    int nn = idx / 96;
    int rr = idx - nn * 96;
    int d = rr >> 5;
    int k = rr & 31;
    float v = pos[nn * 3 + d];
    float omega = expf(-0.28782313662425575f * (float)k);  // ln(10000)/32
    float a = v * omega;
    __hip_bfloat16* o = outp + (size_t)nn * stride + coloff + d * 64 + k;
    o[0]  = __float2bfloat16(sinf(a));
    o[32] = __float2bfloat16(cosf(a));
}

// ---------------- layer 1: h1 = gelu(x @ w1 + b1), K=16 ----------------
__global__ void lin1_kernel(const float* __restrict__ x, const float* __restrict__ w,
                            const float* __restrict__ b, __hip_bfloat16* __restrict__ h1) {
    int idx = blockIdx.x * blockDim.x + threadIdx.x;
    if (idx >= NMESH * HID) return;
    int m = idx / HID;
    int n = idx - m * HID;
    float acc = b[n];
    const float* xr = x + m * 16;
    #pragma unroll
    for (int k = 0; k < 16; k++) acc = fmaf(xr[k], w[k * HID + n], acc);
    h1[idx] = __float2bfloat16(gelu_f(acc));
}

// ---------------- 128x128-tile bf16 MFMA GEMM (round-6 proven body) ----------------
// BK=32, 4 waves (2x2), 16x16x32 MFMA, double-buffered LDS, pre-swizzled
// global_load_lds (0 bank conflicts measured). C = act(A @ Wt^T + bias).
template<bool GATHER, bool GELU, bool F32OUT>
__launch_bounds__(256, 4)
__global__ void mfma_gemm(const __hip_bfloat16* __restrict__ A,
                          const __hip_bfloat16* __restrict__ Wt,
                          const float* __restrict__ bias,
                          void* __restrict__ Cv,
                          int M, int N, int K, int ldc,
                          const int* __restrict__ edges,
                          const __hip_bfloat16* __restrict__ meshf,
                          const __hip_bfloat16* __restrict__ gridf) {
    __shared__ __align__(16) __hip_bfloat16 As[2][4096];
    __shared__ __align__(16) __hip_bfloat16 Bs[2][4096];

    const int t = threadIdx.x;
    const int lane = t & 63;
    const int wave = t >> 6;
    const int wm0 = (wave >> 1) * 64;
    const int wn0 = (wave & 1) * 64;

    int bx, by;
    xcd_swizzle(bx, by);
    const int row0 = by * 128;
    const int col0 = bx * 128;

    const int rS0 = t >> 2;
    const int rS1 = rS0 + 64;
    const int kcS = (t & 3) ^ ((t >> 3) & 3);

    const __hip_bfloat16 *aP0, *aP1, *aQ0 = nullptr, *aQ1 = nullptr;
    if constexpr (GATHER) {
        int e0 = min(row0 + rS0, M - 1);
        int e1 = min(row0 + rS1, M - 1);
        aP0 = meshf + (size_t)edges[2 * e0 + 1] * 576;
        aQ0 = gridf + (size_t)edges[2 * e0 + 0] * 192;
        aP1 = meshf + (size_t)edges[2 * e1 + 1] * 576;
        aQ1 = gridf + (size_t)edges[2 * e1 + 0] * 192;
    } else {
        aP0 = A + (size_t)min(row0 + rS0, M - 1) * K;
        aP1 = A + (size_t)min(row0 + rS1, M - 1) * K;
    }
    const __hip_bfloat16* bP0 = Wt + (size_t)(col0 + rS0) * K;
    const __hip_bfloat16* bP1 = Wt + (size_t)(col0 + rS1) * K;

    const int off0 = (wave * 64) * 16;
    const int off1 = (256 + wave * 64) * 16;

    f32x4 acc[4][4] = {};

    const int kq = lane >> 4;
    const int lr = lane & 15;
    const int kqx = kq ^ ((lr >> 1) & 3);
    const int rdA = (wm0 + lr) * 32 + kqx * 8;
    const int rdB = (wn0 + lr) * 32 + kqx * 8;

    const int nsteps = K >> 5;

    auto stage = [&](int ks, int buf) {
        int k = ks * 32 + kcS * 8;
        const __hip_bfloat16 *sa0, *sa1;
        if constexpr (GATHER) {
            sa0 = (k < 576) ? (aP0 + k) : (aQ0 + (k - 576));
            sa1 = (k < 576) ? (aP1 + k) : (aQ1 + (k - 576));
        } else {
            sa0 = aP0 + k;
            sa1 = aP1 + k;
        }
        load_lds16(sa0, (char*)As[buf] + off0);
        load_lds16(sa1, (char*)As[buf] + off1);
        load_lds16(bP0 + k, (char*)Bs[buf] + off0);
        load_lds16(bP1 + k, (char*)Bs[buf] + off1);
    };

    stage(0, 0);
    __syncthreads();

    int cur = 0;
    for (int ks = 0; ks < nsteps; ks++) {
        if (ks + 1 < nsteps) stage(ks + 1, cur ^ 1);

        bfrag aF[4], bF[4];
        #pragma unroll
        for (int i = 0; i < 4; i++) {
            aF[i] = *reinterpret_cast<const bfrag*>(&As[cur][rdA + i * 512]);
            bF[i] = *reinterpret_cast<const bfrag*>(&Bs[cur][rdB + i * 512]);
        }
        #pragma unroll
        for (int i = 0; i < 4; i++) {
            #pragma unroll
            for (int j = 0; j < 4; j++) {
                acc[i][j] = __builtin_amdgcn_mfma_f32_16x16x32_bf16(aF[i], bF[j], acc[i][j], 0, 0, 0);
            }
        }
        __syncthreads();
        cur ^= 1;
    }

    #pragma unroll
    for (int i = 0; i < 4; i++) {
        #pragma unroll
        for (int j = 0; j < 4; j++) {
            #pragma unroll
            for (int r = 0; r < 4; r++) {
                int row = row0 + wm0 + i * 16 + kq * 4 + r;
                int col = col0 + wn0 + j * 16 + lr;
                if (row < M) {
                    float v = acc[i][j][r] + bias[col];
                    if constexpr (GELU) v = gelu_f(v);
                    if constexpr (F32OUT)
                        ((float*)Cv)[(size_t)row * ldc + col] = v;
                    else
                        ((__hip_bfloat16*)Cv)[(size_t)row * ldc + col] = __float2bfloat16(v);
                }
            }
        }
    }
}

// ---------------- m1 fuse: m1c[e] = gelu(U[mesh_idx[e]] + V[grid_idx[e]]) ----------------
__global__ void fuse_m1(const __hip_bfloat16* __restrict__ U, const __hip_bfloat16* __restrict__ V,
                        const int* __restrict__ edges, int e0, __hip_bfloat16* __restrict__ m1c) {
    int idx = blockIdx.x * blockDim.x + threadIdx.x;   // CHUNK*96 threads, 8 elems each
    if (idx >= CHUNK * 96) return;
    int e = idx / 96;
    int c8 = (idx - e * 96) * 8;
    int ge = e0 + e;
    int mi = edges[2 * ge + 1];
    int gi = edges[2 * ge + 0];
    bfrag u = *reinterpret_cast<const bfrag*>(U + (size_t)mi * 768 + c8);
    bfrag v = *reinterpret_cast<const bfrag*>(V + (size_t)gi * 768 + c8);
    bfrag o;
    #pragma unroll
    for (int i = 0; i < 8; i++) {
        unsigned short ub = (unsigned short)u[i], vb = (unsigned short)v[i];
        float a = __bfloat162float(*(__hip_bfloat16*)&ub) + __bfloat162float(*(__hip_bfloat16*)&vb);
        a = gelu_f(a);
        __hip_bfloat16 hb = __float2bfloat16(a);
        o[i] = *(short*)&hb;
    }
    *reinterpret_cast<bfrag*>(m1c + (size_t)e * 768 + c8) = o;
}

// ---------------- per-chunk 768-wide segment partial sums (f32) ----------------
__global__ void seg768(const int* __restrict__ edges, int e0, int e1,
                       const __hip_bfloat16* __restrict__ m2c, float* __restrict__ sums) {
    int g = blockIdx.x;
    int l = e0, r = e1;
    while (l < r) { int m = (l + r) >> 1; if (edges[2 * m] < g) l = m + 1; else r = m; }
    int lo = l;
    r = e1;
    while (l < r) { int m = (l + r) >> 1; if (edges[2 * m] <= g) l = m + 1; else r = m; }
    int hi = l;
    if (lo >= hi) return;

    int c = threadIdx.x;   // 256 threads, 3 cols each
    float s0 = 0.f, s1 = 0.f, s2 = 0.f;
    for (int e = lo; e < hi; e++) {
        const __hip_bfloat16* rp = m2c + (size_t)(e - e0) * 768;
        s0 += __bfloat162float(rp[c]);
        s1 += __bfloat162float(rp[c + 256]);
        s2 += __bfloat162float(rp[c + 512]);
    }
    float* srow = sums + (size_t)g * 768;
    srow[c] += s0;
    srow[c + 256] += s1;
    srow[c + 512] += s2;
}

// ---------------- per-grid-cell edge count ----------------
__global__ void calc_cnt(const int* __restrict__ edges, int* __restrict__ cnt) {
    int g = blockIdx.x * blockDim.x + threadIdx.x;
    if (g >= GRIDN) return;
    int l = 0, r = NEDGE;
    while (l < r) { int m = (l + r) >> 1; if (edges[2 * m] < g) l = m + 1; else r = m; }
    int lo = l;
    r = NEDGE;
    while (l < r) { int m = (l + r) >> 1; if (edges[2 * m] <= g) l = m + 1; else r = m; }
    cnt[g] = l - lo;
}

// ---------------- meanM2 = bf16(sums / max(cnt,1)) ----------------
__global__ void mean_bf16(const float* __restrict__ sums, const int* __restrict__ cnt,
                          __hip_bfloat16* __restrict__ mm) {
    int idx = blockIdx.x * blockDim.x + threadIdx.x;   // 4 elems each
    int base = idx * 4;
    if (base >= GRIDN * 768) return;
    int g = base / 768;
    float inv = 1.0f / (float)max(cnt[g], 1);
    float4 v = *reinterpret_cast<const float4*>(sums + base);
    __hip_bfloat16 o[4] = {__float2bfloat16(v.x * inv), __float2bfloat16(v.y * inv),
                           __float2bfloat16(v.z * inv), __float2bfloat16(v.w * inv)};
    *reinterpret_cast<uint2*>(mm + base) = *reinterpret_cast<const uint2*>(o);
}

// ---------------- zero output rows of empty segments (bias was added unconditionally) ----------------
__global__ void fix_empty(const int* __restrict__ cnt, float* __restrict__ out) {
    int g = blockIdx.x * blockDim.x + threadIdx.x;
    if (g >= GRIDN || cnt[g] != 0) return;
    float* row = out + (size_t)g * HID;
    for (int c = 0; c < HID; c++) row[c] = 0.f;
}

// ---------------- fallback path kernels (round-6, proven) ----------------
__global__ void seg_partial(const int* __restrict__ edges, int e0, int e1,
                            const __hip_bfloat16* __restrict__ m3c, float* __restrict__ out) {
    int g = blockIdx.x;
    int l = e0, r = e1;
    while (l < r) { int mid = (l + r) >> 1; if (edges[2 * mid] < g) l = mid + 1; else r = mid; }
    int lo = l;
    r = e1;
    while (l < r) { int mid = (l + r) >> 1; if (edges[2 * mid] <= g) l = mid + 1; else r = mid; }
    int hi = l;
    if (lo >= hi) return;
    int c = threadIdx.x;
    float s0 = 0.f, s1 = 0.f, s2 = 0.f;
    for (int e = lo; e < hi; e++) {
        const __hip_bfloat16* rp = m3c + (size_t)(e - e0) * HID;
        s0 += __bfloat162float(rp[c]);
        s1 += __bfloat162float(rp[c + 128]);
        s2 += __bfloat162float(rp[c + 256]);
    }
    float* orow = out + (size_t)g * HID;
    orow[c] += s0;
    orow[c + 128] += s1;
    orow[c + 256] += s2;
}

__global__ void seg_div(const int* __restrict__ edges, float* __restrict__ out) {
    int g = blockIdx.x;
    int l = 0, r = NEDGE;
    while (l < r) { int mid = (l + r) >> 1; if (edges[2 * mid] < g) l = mid + 1; else r = mid; }
    int lo = l;
    r = NEDGE;
    while (l < r) { int mid = (l + r) >> 1; if (edges[2 * mid] <= g) l = mid + 1; else r = mid; }
    int cnt = l - lo;
    float inv = 1.0f / (float)max(cnt, 1);
    int c = threadIdx.x;
    float* orow = out + (size_t)g * HID;
    orow[c] *= inv;
    orow[c + 128] *= inv;
    orow[c + 256] *= inv;
}

extern "C" void kernel_launch(void* const* d_in, const int* in_sizes, int n_in,
                              void* d_out, int out_size, void* d_ws, size_t ws_size,
                              hipStream_t stream) {
    const float* x        = (const float*)d_in[0];
    const float* mesh_pos = (const float*)d_in[1];
    const float* grid_pos = (const float*)d_in[2];
    const int*   edges    = (const int*)d_in[3];
    const float* w1  = (const float*)d_in[4];
    const float* b1  = (const float*)d_in[5];
    const float* w2  = (const float*)d_in[6];
    const float* b2  = (const float*)d_in[7];
    const float* w3  = (const float*)d_in[8];
    const float* b3  = (const float*)d_in[9];
    const float* wm1 = (const float*)d_in[10];
    const float* bm1 = (const float*)d_in[11];
    const float* wm2 = (const float*)d_in[12];
    const float* bm2 = (const float*)d_in[13];
    const float* wm3 = (const float*)d_in[14];
    const float* bm3 = (const float*)d_in[15];
    float* out = (float*)d_out;

    auto rnd = [](size_t b) { return (b + 255) & ~(size_t)255; };
    // new-path footprint: weights ~3.7MB + U 76.8 + V 50.33 + m1m2 100.66 + sums 100.66
    const size_t NEED =
        rnd((size_t)384 * 384 * 2) * 2 + rnd((size_t)768 * 576 * 2) + rnd((size_t)768 * 192 * 2) +
        rnd((size_t)768 * 768 * 2) + rnd((size_t)384 * 768 * 2) + rnd(768 * 4) + rnd(GRIDN * 4) +
        rnd((size_t)NMESH * 768 * 2) + rnd((size_t)GRIDN * 768 * 2) +
        rnd((size_t)CHUNK * 768 * 2) * 2 + rnd((size_t)GRIDN * 768 * 4);

    char* p = (char*)d_ws;
    auto alloc = [&](size_t b) { char* r = p; p += (b + 255) & ~(size_t)255; return r; };

    if (ws_size >= NEED) {
        // ================= NEW PATH (U/V decomposition + linear-m3 folding) =================
        __hip_bfloat16* wt2   = (__hip_bfloat16*)alloc((size_t)384 * 384 * 2);
        __hip_bfloat16* wt3   = (__hip_bfloat16*)alloc((size_t)384 * 384 * 2);
        __hip_bfloat16* wtm1u = (__hip_bfloat16*)alloc((size_t)768 * 576 * 2);  // [n=768][k=576]
        __hip_bfloat16* wtm1v = (__hip_bfloat16*)alloc((size_t)768 * 192 * 2);  // [n=768][k=192]
        __hip_bfloat16* wtm2  = (__hip_bfloat16*)alloc((size_t)768 * 768 * 2);
        __hip_bfloat16* wtm3  = (__hip_bfloat16*)alloc((size_t)384 * 768 * 2);
        float* zeros          = (float*)alloc(768 * 4);
        int* cnt              = (int*)alloc(GRIDN * 4);
        __hip_bfloat16* U     = (__hip_bfloat16*)alloc((size_t)NMESH * 768 * 2);  // 76.8MB
        __hip_bfloat16* V     = (__hip_bfloat16*)alloc((size_t)GRIDN * 768 * 2);  // 50.33MB
        char* m1m2            = alloc(rnd((size_t)CHUNK * 768 * 2) * 2);          // 100.66MB
        float* sums           = (float*)alloc((size_t)GRIDN * 768 * 4);           // 100.66MB

        __hip_bfloat16* m1c   = (__hip_bfloat16*)m1m2;
        __hip_bfloat16* m2c   = (__hip_bfloat16*)(m1m2 + rnd((size_t)CHUNK * 768 * 2));
        __hip_bfloat16* meanM2= m1c;                              // reuse after loop
        __hip_bfloat16* meshf = (__hip_bfloat16*)m1m2;            // 57.6MB, dead before loop
        __hip_bfloat16* gridf = (__hip_bfloat16*)((char*)sums + 50331648);  // dead before memset
        __hip_bfloat16* h1    = (__hip_bfloat16*)sums;            // dead before memset
        __hip_bfloat16* h2    = (__hip_bfloat16*)V;               // dead before V written

        hipMemsetAsync(zeros, 0, 768 * 4, stream);

        transpose_to_bf16<<<(384 * 384 + 255) / 256, 256, 0, stream>>>(w2, wt2, 384, 384, 0);
        transpose_to_bf16<<<(384 * 384 + 255) / 256, 256, 0, stream>>>(w3, wt3, 384, 384, 0);
        transpose_to_bf16<<<(768 * 576 + 255) / 256, 256, 0, stream>>>(wm1, wtm1u, 576, 768, 0);
        transpose_to_bf16<<<(768 * 192 + 255) / 256, 256, 0, stream>>>(wm1, wtm1v, 192, 768, 576);
        transpose_to_bf16<<<(768 * 768 + 255) / 256, 256, 0, stream>>>(wm2, wtm2, 768, 768, 0);
        transpose_to_bf16<<<(768 * 384 + 255) / 256, 256, 0, stream>>>(wm3, wtm3, 768, 384, 0);

        embed_kernel<<<(NMESH * 96 + 255) / 256, 256, 0, stream>>>(mesh_pos, meshf, NMESH, 576, 384);
        embed_kernel<<<(GRIDN * 96 + 255) / 256, 256, 0, stream>>>(grid_pos, gridf, GRIDN, 192, 0);

        lin1_kernel<<<(NMESH * HID + 255) / 256, 256, 0, stream>>>(x, w1, b1, h1);

        // h2 = gelu(h1 @ w2 + b2)
        mfma_gemm<false, true, false><<<dim3(3, 391), 256, 0, stream>>>(
            h1, wt2, b2, h2, NMESH, 384, 384, 384, nullptr, nullptr, nullptr);
        // meshf[:, :384] = h2 @ w3 + b3
        mfma_gemm<false, false, false><<<dim3(3, 391), 256, 0, stream>>>(
            h2, wt3, b3, meshf, NMESH, 384, 384, 576, nullptr, nullptr, nullptr);
        // U = meshf @ wm1[:576] + bm1   (no gelu)
        mfma_gemm<false, false, false><<<dim3(6, 391), 256, 0, stream>>>(
            meshf, wtm1u, bm1, U, NMESH, 768, 576, 768, nullptr, nullptr, nullptr);
        // V = gridf @ wm1[576:]          (no bias, no gelu)
        mfma_gemm<false, false, false><<<dim3(6, 256), 256, 0, stream>>>(
            gridf, wtm1v, zeros, V, GRIDN, 768, 192, 768, nullptr, nullptr, nullptr);

        hipMemsetAsync(sums, 0, (size_t)GRIDN * 768 * 4, stream);

        for (int c = 0; c < NCHUNK; c++) {
            int e0 = c * CHUNK;
            fuse_m1<<<(CHUNK * 96 + 255) / 256, 256, 0, stream>>>(U, V, edges, e0, m1c);
            mfma_gemm<false, true, false><<<dim3(6, CHUNK / 128), 256, 0, stream>>>(
                m1c, wtm2, bm2, m2c, CHUNK, 768, 768, 768, nullptr, nullptr, nullptr);
            seg768<<<GRIDN, 256, 0, stream>>>(edges, e0, e0 + CHUNK, m2c, sums);
        }

        calc_cnt<<<(GRIDN + 255) / 256, 256, 0, stream>>>(edges, cnt);
        mean_bf16<<<(GRIDN * 768 / 4 + 255) / 256, 256, 0, stream>>>(sums, cnt, meanM2);
        // out = meanM2 @ wm3 + bm3  (f32 output, direct to d_out)
        mfma_gemm<false, false, true><<<dim3(3, 256), 256, 0, stream>>>(
            meanM2, wtm3, bm3, out, GRIDN, 384, 768, 384, nullptr, nullptr, nullptr);
        fix_empty<<<(GRIDN + 255) / 256, 256, 0, stream>>>(cnt, out);
    } else {
        // ================= FALLBACK (round-6 proven, ~174MB) =================
        __hip_bfloat16* wt2   = (__hip_bfloat16*)alloc((size_t)384 * 384 * 2);
        __hip_bfloat16* wt3   = (__hip_bfloat16*)alloc((size_t)384 * 384 * 2);
        __hip_bfloat16* wtm1  = (__hip_bfloat16*)alloc((size_t)768 * 768 * 2);
        __hip_bfloat16* wtm2  = (__hip_bfloat16*)alloc((size_t)768 * 768 * 2);
        __hip_bfloat16* wtm3  = (__hip_bfloat16*)alloc((size_t)384 * 768 * 2);
        __hip_bfloat16* gridf = (__hip_bfloat16*)alloc((size_t)GRIDN * 192 * 2);
        __hip_bfloat16* meshf = (__hip_bfloat16*)alloc((size_t)NMESH * 576 * 2);
        char* U1 = alloc((size_t)CHUNK * 768 * 2);
        char* U2 = alloc((size_t)CHUNK * 768 * 2);
        __hip_bfloat16* h1  = (__hip_bfloat16*)U1;
        __hip_bfloat16* h2  = (__hip_bfloat16*)U2;
        __hip_bfloat16* m1c = (__hip_bfloat16*)U1;
        __hip_bfloat16* m2c = (__hip_bfloat16*)U2;
        __hip_bfloat16* m3c = (__hip_bfloat16*)U1;

        hipMemsetAsync(out, 0, (size_t)GRIDN * HID * 4, stream);

        transpose_to_bf16<<<(384 * 384 + 255) / 256, 256, 0, stream>>>(w2, wt2, 384, 384, 0);
        transpose_to_bf16<<<(384 * 384 + 255) / 256, 256, 0, stream>>>(w3, wt3, 384, 384, 0);
        transpose_to_bf16<<<(768 * 768 + 255) / 256, 256, 0, stream>>>(wm1, wtm1, 768, 768, 0);
        transpose_to_bf16<<<(768 * 768 + 255) / 256, 256, 0, stream>>>(wm2, wtm2, 768, 768, 0);
        transpose_to_bf16<<<(768 * 384 + 255) / 256, 256, 0, stream>>>(wm3, wtm3, 768, 384, 0);

        embed_kernel<<<(NMESH * 96 + 255) / 256, 256, 0, stream>>>(mesh_pos, meshf, NMESH, 576, 384);
        embed_kernel<<<(GRIDN * 96 + 255) / 256, 256, 0, stream>>>(grid_pos, gridf, GRIDN, 192, 0);

        lin1_kernel<<<(NMESH * HID + 255) / 256, 256, 0, stream>>>(x, w1, b1, h1);

        mfma_gemm<false, true, false><<<dim3(3, 391), 256, 0, stream>>>(
            h1, wt2, b2, h2, NMESH, 384, 384, 384, nullptr, nullptr, nullptr);
        mfma_gemm<false, false, false><<<dim3(3, 391), 256, 0, stream>>>(
            h2, wt3, b3, meshf, NMESH, 384, 384, 576, nullptr, nullptr, nullptr);

        for (int c = 0; c < NCHUNK; c++) {
            int e0 = c * CHUNK;
            mfma_gemm<true, true, false><<<dim3(6, CHUNK / 128), 256, 0, stream>>>(
                nullptr, wtm1, bm1, m1c, CHUNK, 768, 768, 768, edges + 2 * e0, meshf, gridf);
            mfma_gemm<false, true, false><<<dim3(6, CHUNK / 128), 256, 0, stream>>>(
                m1c, wtm2, bm2, m2c, CHUNK, 768, 768, 768, nullptr, nullptr, nullptr);
            mfma_gemm<false, false, false><<<dim3(3, CHUNK / 128), 256, 0, stream>>>(
                m2c, wtm3, bm3, m3c, CHUNK, 384, 768, 384, nullptr, nullptr, nullptr);
            seg_partial<<<GRIDN, 128, 0, stream>>>(edges, e0, e0 + CHUNK, m3c, out);
        }

        seg_div<<<GRIDN, 128, 0, stream>>>(edges, out);
    }
}

// Round 11
// 1164.238 us; speedup vs baseline: 2.6764x; 1.0355x over previous
//
#include <hip/hip_runtime.h>
#include <hip/hip_bf16.h>

#define NMESH 50000
#define GRIDN 32768
#define NEDGE 131072
#define HID 384
#define CHUNK 32768
#define NCHUNK 4

using f32x4 = __attribute__((ext_vector_type(4))) float;
using bfrag = __attribute__((ext_vector_type(8))) short;

__device__ __forceinline__ float gelu_f(float v) {
    return 0.5f * v * (1.0f + erff(v * 0.70710678118654752f));
}

__device__ __forceinline__ void load_lds16(const void* g, void* l) {
    __builtin_amdgcn_global_load_lds(
        (const __attribute__((address_space(1))) void*)g,
        (__attribute__((address_space(3))) void*)l,
        16, 0, 0);
}

// bijective XCD-chunking swizzle (m204)
__device__ __forceinline__ void xcd_swizzle(int& bx, int& by) {
    int gx = gridDim.x;
    int nwg = gx * gridDim.y;
    int l = blockIdx.y * gx + blockIdx.x;
    int q = nwg >> 3, r = nwg & 7;
    int xcd = l & 7, pos = l >> 3;
    int nl = (xcd < r ? xcd * (q + 1) : r * (q + 1) + (xcd - r) * q) + pos;
    by = nl / gx;
    bx = nl - by * gx;
}

// ---------------- weight transpose + bf16 cast: Wt[n*K+k] = W[k*N+n] ----------------
__global__ void transpose_to_bf16(const float* __restrict__ w, __hip_bfloat16* __restrict__ wt,
                                  int K, int N) {
    int idx = blockIdx.x * blockDim.x + threadIdx.x;
    if (idx >= K * N) return;
    int n = idx / K;
    int k = idx - n * K;
    wt[idx] = __float2bfloat16(w[(size_t)k * N + n]);
}

// ---------------- sincos positional embedding ----------------
__global__ void embed_kernel(const float* __restrict__ pos, __hip_bfloat16* __restrict__ outp,
                             int n, int stride, int coloff) {
    int idx = blockIdx.x * blockDim.x + threadIdx.x;
    if (idx >= n * 96) return;
    int nn = idx / 96;
    int rr = idx - nn * 96;
    int d = rr >> 5;
    int k = rr & 31;
    float v = pos[nn * 3 + d];
    float omega = expf(-0.28782313662425575f * (float)k);  // ln(10000)/32
    float a = v * omega;
    __hip_bfloat16* o = outp + (size_t)nn * stride + coloff + d * 64 + k;
    o[0]  = __float2bfloat16(sinf(a));
    o[32] = __float2bfloat16(cosf(a));
}

// ---------------- layer 1: h1 = gelu(x @ w1 + b1), K=16 ----------------
__global__ void lin1_kernel(const float* __restrict__ x, const float* __restrict__ w,
                            const float* __restrict__ b, __hip_bfloat16* __restrict__ h1) {
    int idx = blockIdx.x * blockDim.x + threadIdx.x;
    if (idx >= NMESH * HID) return;
    int m = idx / HID;
    int n = idx - m * HID;
    float acc = b[n];
    const float* xr = x + m * 16;
    #pragma unroll
    for (int k = 0; k < 16; k++) acc = fmaf(xr[k], w[k * HID + n], acc);
    h1[idx] = __float2bfloat16(gelu_f(acc));
}

// ======================================================================
// 128x128-tile bf16 MFMA GEMM, BK=32, 4 waves (2x2), 16x16x32 MFMA.
// 3-buffer (48KB LDS -> still 3 blocks/CU), prefetch depth 2, counted
// vmcnt(4): at step ks the wait retires tile ks (issued 2 steps ago ->
// ~0 stall); tile ks+1 stays IN FLIGHT across the raw barrier; stage(ks+2)
// issues after the barrier. Hazards: RAW = own vmcnt(4) + barrier (all
// waves' tile-ks writes visible); WAR = buf[(ks+2)%3] last read at step
// ks-1, whose lgkmcnt(0) precedes every wave's barrier arrival.
// Pre-swizzled global_load_lds (measured 0 bank conflicts): physical slot
// p holds (row=p>>2, kc=(p&3)^((p>>3)&3)); fragment reads at
// kqx = kq^((lr>>1)&3).
// ======================================================================
template<bool GATHER, bool GELU>
__launch_bounds__(256, 3)
__global__ void mfma_gemm(const __hip_bfloat16* __restrict__ A,
                          const __hip_bfloat16* __restrict__ Wt,
                          const float* __restrict__ bias,
                          __hip_bfloat16* __restrict__ C,
                          int M, int N, int K, int ldc,
                          const int* __restrict__ edges,
                          const __hip_bfloat16* __restrict__ meshf,
                          const __hip_bfloat16* __restrict__ gridf) {
    __shared__ __align__(16) __hip_bfloat16 As[3][4096];
    __shared__ __align__(16) __hip_bfloat16 Bs[3][4096];

    const int t = threadIdx.x;
    const int lane = t & 63;
    const int wave = t >> 6;
    const int wm0 = (wave >> 1) * 64;
    const int wn0 = (wave & 1) * 64;

    int bx, by;
    xcd_swizzle(bx, by);
    const int row0 = by * 128;
    const int col0 = bx * 128;

    const int rS0 = t >> 2;
    const int rS1 = rS0 + 64;
    const int kcS = (t & 3) ^ ((t >> 3) & 3);

    const __hip_bfloat16 *aP0, *aP1, *aQ0 = nullptr, *aQ1 = nullptr;
    if constexpr (GATHER) {
        int e0 = min(row0 + rS0, M - 1);
        int e1 = min(row0 + rS1, M - 1);
        aP0 = meshf + (size_t)edges[2 * e0 + 1] * 576;
        aQ0 = gridf + (size_t)edges[2 * e0 + 0] * 192;
        aP1 = meshf + (size_t)edges[2 * e1 + 1] * 576;
        aQ1 = gridf + (size_t)edges[2 * e1 + 0] * 192;
    } else {
        aP0 = A + (size_t)min(row0 + rS0, M - 1) * K;
        aP1 = A + (size_t)min(row0 + rS1, M - 1) * K;
    }
    const __hip_bfloat16* bP0 = Wt + (size_t)(col0 + rS0) * K;
    const __hip_bfloat16* bP1 = Wt + (size_t)(col0 + rS1) * K;

    // wave-uniform LDS dest byte bases within a buffer (HW adds lane*16)
    const int off0 = (wave * 64) * 16;
    const int off1 = (256 + wave * 64) * 16;

    f32x4 acc[4][4] = {};

    const int kq = lane >> 4;
    const int lr = lane & 15;
    const int kqx = kq ^ ((lr >> 1) & 3);
    const int rdA = (wm0 + lr) * 32 + kqx * 8;
    const int rdB = (wn0 + lr) * 32 + kqx * 8;

    const int nsteps = K >> 5;   // >= 12 for all shapes here

    auto stage = [&](int ks, int buf) {
        int k = ks * 32 + kcS * 8;
        const __hip_bfloat16 *sa0, *sa1;
        if constexpr (GATHER) {
            sa0 = (k < 576) ? (aP0 + k) : (aQ0 + (k - 576));
            sa1 = (k < 576) ? (aP1 + k) : (aQ1 + (k - 576));
        } else {
            sa0 = aP0 + k;
            sa1 = aP1 + k;
        }
        load_lds16(sa0, (char*)As[buf] + off0);
        load_lds16(sa1, (char*)As[buf] + off1);
        load_lds16(bP0 + k, (char*)Bs[buf] + off0);
        load_lds16(bP1 + k, (char*)Bs[buf] + off1);
    };

    // prologue: stage tiles 0 and 1 (8 loads in flight)
    stage(0, 0);
    stage(1, 1);

    int cur = 0;          // buffer of tile ks
    int stg = 2;          // buffer for tile ks+2
    for (int ks = 0; ks < nsteps; ks++) {
        // retire tile ks (own 4 loads); tile ks+1's 4 stay in flight
        if (ks + 1 < nsteps) {
            asm volatile("s_waitcnt vmcnt(4)" ::: "memory");
        } else {
            asm volatile("s_waitcnt vmcnt(0)" ::: "memory");
        }
        __builtin_amdgcn_s_barrier();   // all waves' tile-ks writes visible; WAR for stg
        if (ks + 2 < nsteps) stage(ks + 2, stg);

        bfrag aF[4], bF[4];
        #pragma unroll
        for (int i = 0; i < 4; i++) {
            aF[i] = *reinterpret_cast<const bfrag*>(&As[cur][rdA + i * 512]);
            bF[i] = *reinterpret_cast<const bfrag*>(&Bs[cur][rdB + i * 512]);
        }
        asm volatile("s_waitcnt lgkmcnt(0)" ::: "memory");
        __builtin_amdgcn_sched_barrier(0);   // rule #18: keep MFMA below the wait
        __builtin_amdgcn_s_setprio(1);
        #pragma unroll
        for (int i = 0; i < 4; i++) {
            #pragma unroll
            for (int j = 0; j < 4; j++) {
                acc[i][j] = __builtin_amdgcn_mfma_f32_16x16x32_bf16(aF[i], bF[j], acc[i][j], 0, 0, 0);
            }
        }
        __builtin_amdgcn_s_setprio(0);

        cur = (cur == 2) ? 0 : cur + 1;
        stg = (stg == 2) ? 0 : stg + 1;
    }

    // C/D layout: col = lane&15, row = (lane>>4)*4 + reg
    #pragma unroll
    for (int i = 0; i < 4; i++) {
        #pragma unroll
        for (int j = 0; j < 4; j++) {
            #pragma unroll
            for (int r = 0; r < 4; r++) {
                int row = row0 + wm0 + i * 16 + kq * 4 + r;
                int col = col0 + wn0 + j * 16 + lr;
                if (row < M) {
                    float v = acc[i][j][r] + bias[col];
                    if constexpr (GELU) v = gelu_f(v);
                    C[(size_t)row * ldc + col] = __float2bfloat16(v);
                }
            }
        }
    }
}

// ---------------- per-chunk segment partial sums (sorted grid_idx, no atomics) ----------------
__global__ void seg_partial(const int* __restrict__ edges, int e0, int e1,
                            const __hip_bfloat16* __restrict__ m3c, float* __restrict__ out) {
    int g = blockIdx.x;
    int l = e0, r = e1;
    while (l < r) { int mid = (l + r) >> 1; if (edges[2 * mid] < g) l = mid + 1; else r = mid; }
    int lo = l;
    r = e1;
    while (l < r) { int mid = (l + r) >> 1; if (edges[2 * mid] <= g) l = mid + 1; else r = mid; }
    int hi = l;
    if (lo >= hi) return;

    int c = threadIdx.x;
    float s0 = 0.f, s1 = 0.f, s2 = 0.f;
    for (int e = lo; e < hi; e++) {
        const __hip_bfloat16* rp = m3c + (size_t)(e - e0) * HID;
        s0 += __bfloat162float(rp[c]);
        s1 += __bfloat162float(rp[c + 128]);
        s2 += __bfloat162float(rp[c + 256]);
    }
    float* orow = out + (size_t)g * HID;
    orow[c] += s0;
    orow[c + 128] += s1;
    orow[c + 256] += s2;
}

// ---------------- final divide by segment count ----------------
__global__ void seg_div(const int* __restrict__ edges, float* __restrict__ out) {
    int g = blockIdx.x;
    int l = 0, r = NEDGE;
    while (l < r) { int mid = (l + r) >> 1; if (edges[2 * mid] < g) l = mid + 1; else r = mid; }
    int lo = l;
    r = NEDGE;
    while (l < r) { int mid = (l + r) >> 1; if (edges[2 * mid] <= g) l = mid + 1; else r = mid; }
    int cnt = l - lo;
    float inv = 1.0f / (float)max(cnt, 1);
    int c = threadIdx.x;
    float* orow = out + (size_t)g * HID;
    orow[c] *= inv;
    orow[c + 128] *= inv;
    orow[c + 256] *= inv;
}

extern "C" void kernel_launch(void* const* d_in, const int* in_sizes, int n_in,
                              void* d_out, int out_size, void* d_ws, size_t ws_size,
                              hipStream_t stream) {
    const float* x        = (const float*)d_in[0];
    const float* mesh_pos = (const float*)d_in[1];
    const float* grid_pos = (const float*)d_in[2];
    const int*   edges    = (const int*)d_in[3];
    const float* w1  = (const float*)d_in[4];
    const float* b1  = (const float*)d_in[5];
    const float* w2  = (const float*)d_in[6];
    const float* b2  = (const float*)d_in[7];
    const float* w3  = (const float*)d_in[8];
    const float* b3  = (const float*)d_in[9];
    const float* wm1 = (const float*)d_in[10];
    const float* bm1 = (const float*)d_in[11];
    const float* wm2 = (const float*)d_in[12];
    const float* bm2 = (const float*)d_in[13];
    const float* wm3 = (const float*)d_in[14];
    const float* bm3 = (const float*)d_in[15];
    float* out = (float*)d_out;

    // ---- workspace layout, ~174 MB total (proven) ----
    char* p = (char*)d_ws;
    auto alloc = [&](size_t b) { char* r = p; p += (b + 255) & ~(size_t)255; return r; };
    __hip_bfloat16* wt2   = (__hip_bfloat16*)alloc((size_t)384 * 384 * 2);
    __hip_bfloat16* wt3   = (__hip_bfloat16*)alloc((size_t)384 * 384 * 2);
    __hip_bfloat16* wtm1  = (__hip_bfloat16*)alloc((size_t)768 * 768 * 2);
    __hip_bfloat16* wtm2  = (__hip_bfloat16*)alloc((size_t)768 * 768 * 2);
    __hip_bfloat16* wtm3  = (__hip_bfloat16*)alloc((size_t)384 * 768 * 2);
    __hip_bfloat16* gridf = (__hip_bfloat16*)alloc((size_t)GRIDN * 192 * 2);
    __hip_bfloat16* meshf = (__hip_bfloat16*)alloc((size_t)NMESH * 576 * 2);
    char* U1 = alloc((size_t)CHUNK * 768 * 2);
    char* U2 = alloc((size_t)CHUNK * 768 * 2);
    __hip_bfloat16* h1  = (__hip_bfloat16*)U1;
    __hip_bfloat16* h2  = (__hip_bfloat16*)U2;
    __hip_bfloat16* m1c = (__hip_bfloat16*)U1;
    __hip_bfloat16* m2c = (__hip_bfloat16*)U2;
    __hip_bfloat16* m3c = (__hip_bfloat16*)U1;  // m1c dead once m2c computed

    hipMemsetAsync(out, 0, (size_t)GRIDN * HID * 4, stream);

    transpose_to_bf16<<<(384 * 384 + 255) / 256, 256, 0, stream>>>(w2, wt2, 384, 384);
    transpose_to_bf16<<<(384 * 384 + 255) / 256, 256, 0, stream>>>(w3, wt3, 384, 384);
    transpose_to_bf16<<<(768 * 768 + 255) / 256, 256, 0, stream>>>(wm1, wtm1, 768, 768);
    transpose_to_bf16<<<(768 * 768 + 255) / 256, 256, 0, stream>>>(wm2, wtm2, 768, 768);
    transpose_to_bf16<<<(768 * 384 + 255) / 256, 256, 0, stream>>>(wm3, wtm3, 768, 384);

    embed_kernel<<<(NMESH * 96 + 255) / 256, 256, 0, stream>>>(mesh_pos, meshf, NMESH, 576, 384);
    embed_kernel<<<(GRIDN * 96 + 255) / 256, 256, 0, stream>>>(grid_pos, gridf, GRIDN, 192, 0);

    lin1_kernel<<<(NMESH * HID + 255) / 256, 256, 0, stream>>>(x, w1, b1, h1);

    // h2 = gelu(h1 @ w2 + b2)
    mfma_gemm<false, true><<<dim3(3, 391), 256, 0, stream>>>(
        h1, wt2, b2, h2, NMESH, 384, 384, 384, nullptr, nullptr, nullptr);
    // mesh_feat[:, :384] = h2 @ w3 + b3
    mfma_gemm<false, false><<<dim3(3, 391), 256, 0, stream>>>(
        h2, wt3, b3, meshf, NMESH, 384, 384, 576, nullptr, nullptr, nullptr);

    for (int c = 0; c < NCHUNK; c++) {
        int e0 = c * CHUNK;
        // m1c = gelu(gather(edges[e0:e0+CHUNK]) @ wm1 + bm1)
        mfma_gemm<true, true><<<dim3(6, CHUNK / 128), 256, 0, stream>>>(
            nullptr, wtm1, bm1, m1c, CHUNK, 768, 768, 768, edges + 2 * e0, meshf, gridf);
        // m2c = gelu(m1c @ wm2 + bm2)
        mfma_gemm<false, true><<<dim3(6, CHUNK / 128), 256, 0, stream>>>(
            m1c, wtm2, bm2, m2c, CHUNK, 768, 768, 768, nullptr, nullptr, nullptr);
        // m3c = m2c @ wm3 + bm3   (overwrites m1c region — m1c dead)
        mfma_gemm<false, false><<<dim3(3, CHUNK / 128), 256, 0, stream>>>(
            m2c, wtm3, bm3, m3c, CHUNK, 384, 768, 384, nullptr, nullptr, nullptr);
        // accumulate segment sums for this chunk
        seg_partial<<<GRIDN, 128, 0, stream>>>(edges, e0, e0 + CHUNK, m3c, out);
    }

    seg_div<<<GRIDN, 128, 0, stream>>>(edges, out);
}

// Round 12
// 1102.168 us; speedup vs baseline: 2.8271x; 1.0563x over previous
//
#include <hip/hip_runtime.h>
#include <hip/hip_bf16.h>

#define NMESH 50000
#define GRIDN 32768
#define NEDGE 131072
#define HID 384

using f32x4 = __attribute__((ext_vector_type(4))) float;
using bfrag = __attribute__((ext_vector_type(8))) short;

__device__ __forceinline__ float gelu_f(float v) {
    return 0.5f * v * (1.0f + erff(v * 0.70710678118654752f));
}

__device__ __forceinline__ void load_lds16(const void* g, void* l) {
    __builtin_amdgcn_global_load_lds(
        (const __attribute__((address_space(1))) void*)g,
        (__attribute__((address_space(3))) void*)l,
        16, 0, 0);
}

// bijective XCD-chunking swizzle (m204)
__device__ __forceinline__ void xcd_swizzle(int& bx, int& by) {
    int gx = gridDim.x;
    int nwg = gx * gridDim.y;
    int l = blockIdx.y * gx + blockIdx.x;
    int q = nwg >> 3, r = nwg & 7;
    int xcd = l & 7, pos = l >> 3;
    int nl = (xcd < r ? xcd * (q + 1) : r * (q + 1) + (xcd - r) * q) + pos;
    by = nl / gx;
    bx = nl - by * gx;
}

// ---------------- weight transpose + bf16 cast: wt[n*K+k] = w[(k0+k)*N+n] ----------------
__global__ void transpose_to_bf16(const float* __restrict__ w, __hip_bfloat16* __restrict__ wt,
                                  int K, int N, int k0) {
    int idx = blockIdx.x * blockDim.x + threadIdx.x;
    if (idx >= K * N) return;
    int n = idx / K;
    int k = idx - n * K;
    wt[idx] = __float2bfloat16(w[(size_t)(k0 + k) * N + n]);
}

// ---------------- sincos positional embedding ----------------
__global__ void embed_kernel(const float* __restrict__ pos, __hip_bfloat16* __restrict__ outp,
                             int n, int stride, int coloff) {
    int idx = blockIdx.x * blockDim.x + threadIdx.x;
    if (idx >= n * 96) return;
    int nn = idx / 96;
    int rr = idx - nn * 96;
    int d = rr >> 5;
    int k = rr & 31;
    float v = pos[nn * 3 + d];
    float omega = expf(-0.28782313662425575f * (float)k);  // ln(10000)/32
    float a = v * omega;
    __hip_bfloat16* o = outp + (size_t)nn * stride + coloff + d * 64 + k;
    o[0]  = __float2bfloat16(sinf(a));
    o[32] = __float2bfloat16(cosf(a));
}

// ---------------- layer 1: h1 = gelu(x @ w1 + b1), K=16 ----------------
__global__ void lin1_kernel(const float* __restrict__ x, const float* __restrict__ w,
                            const float* __restrict__ b, __hip_bfloat16* __restrict__ h1) {
    int idx = blockIdx.x * blockDim.x + threadIdx.x;
    if (idx >= NMESH * HID) return;
    int m = idx / HID;
    int n = idx - m * HID;
    float acc = b[n];
    const float* xr = x + m * 16;
    #pragma unroll
    for (int k = 0; k < 16; k++) acc = fmaf(xr[k], w[k * HID + n], acc);
    h1[idx] = __float2bfloat16(gelu_f(acc));
}

// ======================================================================
// 128x128-tile bf16 MFMA GEMM (round-11 proven body, unchanged).
// 3-buffer counted-vmcnt pipeline, pre-swizzled global_load_lds
// (measured: 0 bank conflicts, no spill, neutral-or-equal vs r6).
// ======================================================================
template<bool GATHER, bool GELU>
__launch_bounds__(256, 3)
__global__ void mfma_gemm(const __hip_bfloat16* __restrict__ A,
                          const __hip_bfloat16* __restrict__ Wt,
                          const float* __restrict__ bias,
                          __hip_bfloat16* __restrict__ C,
                          int M, int N, int K, int ldc,
                          const int* __restrict__ edges,
                          const __hip_bfloat16* __restrict__ meshf,
                          const __hip_bfloat16* __restrict__ gridf) {
    __shared__ __align__(16) __hip_bfloat16 As[3][4096];
    __shared__ __align__(16) __hip_bfloat16 Bs[3][4096];

    const int t = threadIdx.x;
    const int lane = t & 63;
    const int wave = t >> 6;
    const int wm0 = (wave >> 1) * 64;
    const int wn0 = (wave & 1) * 64;

    int bx, by;
    xcd_swizzle(bx, by);
    const int row0 = by * 128;
    const int col0 = bx * 128;

    const int rS0 = t >> 2;
    const int rS1 = rS0 + 64;
    const int kcS = (t & 3) ^ ((t >> 3) & 3);

    const __hip_bfloat16 *aP0, *aP1, *aQ0 = nullptr, *aQ1 = nullptr;
    if constexpr (GATHER) {
        int e0 = min(row0 + rS0, M - 1);
        int e1 = min(row0 + rS1, M - 1);
        aP0 = meshf + (size_t)edges[2 * e0 + 1] * 576;
        aQ0 = gridf + (size_t)edges[2 * e0 + 0] * 192;
        aP1 = meshf + (size_t)edges[2 * e1 + 1] * 576;
        aQ1 = gridf + (size_t)edges[2 * e1 + 0] * 192;
    } else {
        aP0 = A + (size_t)min(row0 + rS0, M - 1) * K;
        aP1 = A + (size_t)min(row0 + rS1, M - 1) * K;
    }
    const __hip_bfloat16* bP0 = Wt + (size_t)(col0 + rS0) * K;
    const __hip_bfloat16* bP1 = Wt + (size_t)(col0 + rS1) * K;

    const int off0 = (wave * 64) * 16;
    const int off1 = (256 + wave * 64) * 16;

    f32x4 acc[4][4] = {};

    const int kq = lane >> 4;
    const int lr = lane & 15;
    const int kqx = kq ^ ((lr >> 1) & 3);
    const int rdA = (wm0 + lr) * 32 + kqx * 8;
    const int rdB = (wn0 + lr) * 32 + kqx * 8;

    const int nsteps = K >> 5;

    auto stage = [&](int ks, int buf) {
        int k = ks * 32 + kcS * 8;
        const __hip_bfloat16 *sa0, *sa1;
        if constexpr (GATHER) {
            sa0 = (k < 576) ? (aP0 + k) : (aQ0 + (k - 576));
            sa1 = (k < 576) ? (aP1 + k) : (aQ1 + (k - 576));
        } else {
            sa0 = aP0 + k;
            sa1 = aP1 + k;
        }
        load_lds16(sa0, (char*)As[buf] + off0);
        load_lds16(sa1, (char*)As[buf] + off1);
        load_lds16(bP0 + k, (char*)Bs[buf] + off0);
        load_lds16(bP1 + k, (char*)Bs[buf] + off1);
    };

    stage(0, 0);
    stage(1, 1);

    int cur = 0;
    int stg = 2;
    for (int ks = 0; ks < nsteps; ks++) {
        if (ks + 1 < nsteps) {
            asm volatile("s_waitcnt vmcnt(4)" ::: "memory");
        } else {
            asm volatile("s_waitcnt vmcnt(0)" ::: "memory");
        }
        __builtin_amdgcn_s_barrier();
        if (ks + 2 < nsteps) stage(ks + 2, stg);

        bfrag aF[4], bF[4];
        #pragma unroll
        for (int i = 0; i < 4; i++) {
            aF[i] = *reinterpret_cast<const bfrag*>(&As[cur][rdA + i * 512]);
            bF[i] = *reinterpret_cast<const bfrag*>(&Bs[cur][rdB + i * 512]);
        }
        asm volatile("s_waitcnt lgkmcnt(0)" ::: "memory");
        __builtin_amdgcn_sched_barrier(0);
        __builtin_amdgcn_s_setprio(1);
        #pragma unroll
        for (int i = 0; i < 4; i++) {
            #pragma unroll
            for (int j = 0; j < 4; j++) {
                acc[i][j] = __builtin_amdgcn_mfma_f32_16x16x32_bf16(aF[i], bF[j], acc[i][j], 0, 0, 0);
            }
        }
        __builtin_amdgcn_s_setprio(0);

        cur = (cur == 2) ? 0 : cur + 1;
        stg = (stg == 2) ? 0 : stg + 1;
    }

    #pragma unroll
    for (int i = 0; i < 4; i++) {
        #pragma unroll
        for (int j = 0; j < 4; j++) {
            #pragma unroll
            for (int r = 0; r < 4; r++) {
                int row = row0 + wm0 + i * 16 + kq * 4 + r;
                int col = col0 + wn0 + j * 16 + lr;
                if (row < M) {
                    float v = acc[i][j][r] + bias[col];
                    if constexpr (GELU) v = gelu_f(v);
                    C[(size_t)row * ldc + col] = __float2bfloat16(v);
                }
            }
        }
    }
}

// ---------------- m1 fuse: m1c[e] = gelu(U[mesh_idx[e]] + V[grid_idx[e]]) ----------------
__global__ void fuse_m1(const __hip_bfloat16* __restrict__ U, const __hip_bfloat16* __restrict__ V,
                        const int* __restrict__ edges, int e0, int ne,
                        __hip_bfloat16* __restrict__ m1c) {
    int idx = blockIdx.x * blockDim.x + threadIdx.x;
    if (idx >= ne * 96) return;
    int e = idx / 96;
    int c8 = (idx - e * 96) * 8;
    int ge = e0 + e;
    int mi = edges[2 * ge + 1];
    int gi = edges[2 * ge + 0];
    bfrag u = *reinterpret_cast<const bfrag*>(U + (size_t)mi * 768 + c8);
    bfrag v = *reinterpret_cast<const bfrag*>(V + (size_t)gi * 768 + c8);
    bfrag o;
    #pragma unroll
    for (int i = 0; i < 8; i++) {
        unsigned short ub = (unsigned short)u[i], vb = (unsigned short)v[i];
        float a = __bfloat162float(*(__hip_bfloat16*)&ub) + __bfloat162float(*(__hip_bfloat16*)&vb);
        a = gelu_f(a);
        __hip_bfloat16 hb = __float2bfloat16(a);
        o[i] = *(short*)&hb;
    }
    *reinterpret_cast<bfrag*>(m1c + (size_t)e * 768 + c8) = o;
}

// ---------------- per-chunk segment partial sums (sorted grid_idx, no atomics) ----------------
__global__ void seg_partial(const int* __restrict__ edges, int e0, int e1,
                            const __hip_bfloat16* __restrict__ m3c, float* __restrict__ out) {
    int g = blockIdx.x;
    int l = e0, r = e1;
    while (l < r) { int mid = (l + r) >> 1; if (edges[2 * mid] < g) l = mid + 1; else r = mid; }
    int lo = l;
    r = e1;
    while (l < r) { int mid = (l + r) >> 1; if (edges[2 * mid] <= g) l = mid + 1; else r = mid; }
    int hi = l;
    if (lo >= hi) return;

    int c = threadIdx.x;
    float s0 = 0.f, s1 = 0.f, s2 = 0.f;
    for (int e = lo; e < hi; e++) {
        const __hip_bfloat16* rp = m3c + (size_t)(e - e0) * HID;
        s0 += __bfloat162float(rp[c]);
        s1 += __bfloat162float(rp[c + 128]);
        s2 += __bfloat162float(rp[c + 256]);
    }
    float* orow = out + (size_t)g * HID;
    orow[c] += s0;
    orow[c + 128] += s1;
    orow[c + 256] += s2;
}

// ---------------- final divide by segment count ----------------
__global__ void seg_div(const int* __restrict__ edges, float* __restrict__ out) {
    int g = blockIdx.x;
    int l = 0, r = NEDGE;
    while (l < r) { int mid = (l + r) >> 1; if (edges[2 * mid] < g) l = mid + 1; else r = mid; }
    int lo = l;
    r = NEDGE;
    while (l < r) { int mid = (l + r) >> 1; if (edges[2 * mid] <= g) l = mid + 1; else r = mid; }
    int cnt = l - lo;
    float inv = 1.0f / (float)max(cnt, 1);
    int c = threadIdx.x;
    float* orow = out + (size_t)g * HID;
    orow[c] *= inv;
    orow[c + 128] *= inv;
    orow[c + 256] *= inv;
}

extern "C" void kernel_launch(void* const* d_in, const int* in_sizes, int n_in,
                              void* d_out, int out_size, void* d_ws, size_t ws_size,
                              hipStream_t stream) {
    const float* x        = (const float*)d_in[0];
    const float* mesh_pos = (const float*)d_in[1];
    const float* grid_pos = (const float*)d_in[2];
    const int*   edges    = (const int*)d_in[3];
    const float* w1  = (const float*)d_in[4];
    const float* b1  = (const float*)d_in[5];
    const float* w2  = (const float*)d_in[6];
    const float* b2  = (const float*)d_in[7];
    const float* w3  = (const float*)d_in[8];
    const float* b3  = (const float*)d_in[9];
    const float* wm1 = (const float*)d_in[10];
    const float* bm1 = (const float*)d_in[11];
    const float* wm2 = (const float*)d_in[12];
    const float* bm2 = (const float*)d_in[13];
    const float* wm3 = (const float*)d_in[14];
    const float* bm3 = (const float*)d_in[15];
    float* out = (float*)d_out;

    auto rnd = [](size_t b) { return (b + 255) & ~(size_t)255; };
    const size_t wbytes = rnd((size_t)384 * 384 * 2) * 2 + rnd((size_t)768 * 576 * 2) +
                          rnd((size_t)768 * 192 * 2) + rnd((size_t)768 * 768 * 2) +
                          rnd((size_t)384 * 768 * 2) + rnd(768 * 4);
    const size_t szU    = rnd((size_t)NMESH * 768 * 2);   // 76.8 MB
    const size_t szV    = rnd((size_t)GRIDN * 768 * 2);   // 50.33 MB
    const size_t szMesh = rnd((size_t)NMESH * 576 * 2);   // 57.6 MB
    const size_t szGrid = rnd((size_t)GRIDN * 192 * 2);   // 12.58 MB
    auto caFor = [&](size_t ch) {
        size_t c2 = 2 * rnd(ch * 768 * 2);
        size_t mg = szMesh + szGrid;
        return c2 > mg ? c2 : mg;
    };
    int CH = 0;
    if (ws_size >= wbytes + szU + szV + caFor(32768)) CH = 32768;        // ~231 MB
    else if (ws_size >= wbytes + szU + szV + caFor(16384)) CH = 16384;   // ~201 MB

    char* p = (char*)d_ws;
    auto alloc = [&](size_t b) { char* r = p; p += (b + 255) & ~(size_t)255; return r; };

    if (CH > 0) {
        // ================= U/V DECOMPOSITION PATH =================
        const int NCH = NEDGE / CH;
        __hip_bfloat16* wt2   = (__hip_bfloat16*)alloc((size_t)384 * 384 * 2);
        __hip_bfloat16* wt3   = (__hip_bfloat16*)alloc((size_t)384 * 384 * 2);
        __hip_bfloat16* wtm1u = (__hip_bfloat16*)alloc((size_t)768 * 576 * 2);  // [n=768][k=576]
        __hip_bfloat16* wtm1v = (__hip_bfloat16*)alloc((size_t)768 * 192 * 2);  // [n=768][k=192]
        __hip_bfloat16* wtm2  = (__hip_bfloat16*)alloc((size_t)768 * 768 * 2);
        __hip_bfloat16* wtm3  = (__hip_bfloat16*)alloc((size_t)384 * 768 * 2);
        float* zeros          = (float*)alloc(768 * 4);
        char* Ur              = alloc(szU);
        char* Vr              = alloc(szV);
        char* CA              = alloc(caFor(CH));

        __hip_bfloat16* U     = (__hip_bfloat16*)Ur;
        __hip_bfloat16* V     = (__hip_bfloat16*)Vr;
        __hip_bfloat16* h1    = (__hip_bfloat16*)Ur;                    // [0, 38.4MB)
        __hip_bfloat16* h2    = (__hip_bfloat16*)(Ur + 38400000);       // [38.4, 76.8)
        __hip_bfloat16* meshf = (__hip_bfloat16*)CA;                    // dead after U-GEMM
        __hip_bfloat16* gridf = (__hip_bfloat16*)(CA + szMesh);         // dead after V-GEMM
        __hip_bfloat16* m1c   = (__hip_bfloat16*)CA;
        __hip_bfloat16* m2c   = (__hip_bfloat16*)(CA + rnd((size_t)CH * 768 * 2));
        __hip_bfloat16* m3c   = m1c;                                    // m1c dead once m2c done

        hipMemsetAsync(zeros, 0, 768 * 4, stream);
        hipMemsetAsync(out, 0, (size_t)GRIDN * HID * 4, stream);

        transpose_to_bf16<<<(384 * 384 + 255) / 256, 256, 0, stream>>>(w2, wt2, 384, 384, 0);
        transpose_to_bf16<<<(384 * 384 + 255) / 256, 256, 0, stream>>>(w3, wt3, 384, 384, 0);
        transpose_to_bf16<<<(768 * 576 + 255) / 256, 256, 0, stream>>>(wm1, wtm1u, 576, 768, 0);
        transpose_to_bf16<<<(768 * 192 + 255) / 256, 256, 0, stream>>>(wm1, wtm1v, 192, 768, 576);
        transpose_to_bf16<<<(768 * 768 + 255) / 256, 256, 0, stream>>>(wm2, wtm2, 768, 768, 0);
        transpose_to_bf16<<<(768 * 384 + 255) / 256, 256, 0, stream>>>(wm3, wtm3, 768, 384, 0);

        embed_kernel<<<(NMESH * 96 + 255) / 256, 256, 0, stream>>>(mesh_pos, meshf, NMESH, 576, 384);
        embed_kernel<<<(GRIDN * 96 + 255) / 256, 256, 0, stream>>>(grid_pos, gridf, GRIDN, 192, 0);

        lin1_kernel<<<(NMESH * HID + 255) / 256, 256, 0, stream>>>(x, w1, b1, h1);

        // h2 = gelu(h1 @ w2 + b2)        (reads Ur[0:38.4), writes Ur[38.4:76.8))
        mfma_gemm<false, true><<<dim3(3, 391), 256, 0, stream>>>(
            h1, wt2, b2, h2, NMESH, 384, 384, 384, nullptr, nullptr, nullptr);
        // meshf[:, :384] = h2 @ w3 + b3
        mfma_gemm<false, false><<<dim3(3, 391), 256, 0, stream>>>(
            h2, wt3, b3, meshf, NMESH, 384, 384, 576, nullptr, nullptr, nullptr);
        // U = meshf @ wm1[:576] + bm1    (overwrites h1/h2 — both dead)
        mfma_gemm<false, false><<<dim3(6, 391), 256, 0, stream>>>(
            meshf, wtm1u, bm1, U, NMESH, 768, 576, 768, nullptr, nullptr, nullptr);
        // V = gridf @ wm1[576:]
        mfma_gemm<false, false><<<dim3(6, 256), 256, 0, stream>>>(
            gridf, wtm1v, zeros, V, GRIDN, 768, 192, 768, nullptr, nullptr, nullptr);

        for (int c = 0; c < NCH; c++) {
            int e0 = c * CH;
            fuse_m1<<<(CH * 96 + 255) / 256, 256, 0, stream>>>(U, V, edges, e0, CH, m1c);
            mfma_gemm<false, true><<<dim3(6, CH / 128), 256, 0, stream>>>(
                m1c, wtm2, bm2, m2c, CH, 768, 768, 768, nullptr, nullptr, nullptr);
            mfma_gemm<false, false><<<dim3(3, CH / 128), 256, 0, stream>>>(
                m2c, wtm3, bm3, m3c, CH, 384, 768, 384, nullptr, nullptr, nullptr);
            seg_partial<<<GRIDN, 128, 0, stream>>>(edges, e0, e0 + CH, m3c, out);
        }

        seg_div<<<GRIDN, 128, 0, stream>>>(edges, out);
    } else {
        // ================= FALLBACK (round-11 proven, ~174 MB) =================
        __hip_bfloat16* wt2   = (__hip_bfloat16*)alloc((size_t)384 * 384 * 2);
        __hip_bfloat16* wt3   = (__hip_bfloat16*)alloc((size_t)384 * 384 * 2);
        __hip_bfloat16* wtm1  = (__hip_bfloat16*)alloc((size_t)768 * 768 * 2);
        __hip_bfloat16* wtm2  = (__hip_bfloat16*)alloc((size_t)768 * 768 * 2);
        __hip_bfloat16* wtm3  = (__hip_bfloat16*)alloc((size_t)384 * 768 * 2);
        __hip_bfloat16* gridf = (__hip_bfloat16*)alloc((size_t)GRIDN * 192 * 2);
        __hip_bfloat16* meshf = (__hip_bfloat16*)alloc((size_t)NMESH * 576 * 2);
        char* U1 = alloc((size_t)32768 * 768 * 2);
        char* U2 = alloc((size_t)32768 * 768 * 2);
        __hip_bfloat16* h1  = (__hip_bfloat16*)U1;
        __hip_bfloat16* h2  = (__hip_bfloat16*)U2;
        __hip_bfloat16* m1c = (__hip_bfloat16*)U1;
        __hip_bfloat16* m2c = (__hip_bfloat16*)U2;
        __hip_bfloat16* m3c = (__hip_bfloat16*)U1;

        hipMemsetAsync(out, 0, (size_t)GRIDN * HID * 4, stream);

        transpose_to_bf16<<<(384 * 384 + 255) / 256, 256, 0, stream>>>(w2, wt2, 384, 384, 0);
        transpose_to_bf16<<<(384 * 384 + 255) / 256, 256, 0, stream>>>(w3, wt3, 384, 384, 0);
        transpose_to_bf16<<<(768 * 768 + 255) / 256, 256, 0, stream>>>(wm1, wtm1, 768, 768, 0);
        transpose_to_bf16<<<(768 * 768 + 255) / 256, 256, 0, stream>>>(wm2, wtm2, 768, 768, 0);
        transpose_to_bf16<<<(768 * 384 + 255) / 256, 256, 0, stream>>>(wm3, wtm3, 768, 384, 0);

        embed_kernel<<<(NMESH * 96 + 255) / 256, 256, 0, stream>>>(mesh_pos, meshf, NMESH, 576, 384);
        embed_kernel<<<(GRIDN * 96 + 255) / 256, 256, 0, stream>>>(grid_pos, gridf, GRIDN, 192, 0);

        lin1_kernel<<<(NMESH * HID + 255) / 256, 256, 0, stream>>>(x, w1, b1, h1);

        mfma_gemm<false, true><<<dim3(3, 391), 256, 0, stream>>>(
            h1, wt2, b2, h2, NMESH, 384, 384, 384, nullptr, nullptr, nullptr);
        mfma_gemm<false, false><<<dim3(3, 391), 256, 0, stream>>>(
            h2, wt3, b3, meshf, NMESH, 384, 384, 576, nullptr, nullptr, nullptr);

        for (int c = 0; c < 4; c++) {
            int e0 = c * 32768;
            mfma_gemm<true, true><<<dim3(6, 256), 256, 0, stream>>>(
                nullptr, wtm1, bm1, m1c, 32768, 768, 768, 768, edges + 2 * e0, meshf, gridf);
            mfma_gemm<false, true><<<dim3(6, 256), 256, 0, stream>>>(
                m1c, wtm2, bm2, m2c, 32768, 768, 768, 768, nullptr, nullptr, nullptr);
            mfma_gemm<false, false><<<dim3(3, 256), 256, 0, stream>>>(
                m2c, wtm3, bm3, m3c, 32768, 384, 768, 384, nullptr, nullptr, nullptr);
            seg_partial<<<GRIDN, 128, 0, stream>>>(edges, e0, e0 + 32768, m3c, out);
        }

        seg_div<<<GRIDN, 128, 0, stream>>>(edges, out);
    }
}

// Round 13
// 1094.577 us; speedup vs baseline: 2.8467x; 1.0069x over previous
//
#include <hip/hip_runtime.h>
#include <hip/hip_bf16.h>

#define NMESH 50000
#define GRIDN 32768
#define NEDGE 131072
#define HID 384

using f32x4 = __attribute__((ext_vector_type(4))) float;
using bfrag = __attribute__((ext_vector_type(8))) short;

__device__ __forceinline__ float gelu_f(float v) {
    return 0.5f * v * (1.0f + erff(v * 0.70710678118654752f));
}

__device__ __forceinline__ void load_lds16(const void* g, void* l) {
    __builtin_amdgcn_global_load_lds(
        (const __attribute__((address_space(1))) void*)g,
        (__attribute__((address_space(3))) void*)l,
        16, 0, 0);
}

// bijective XCD-chunking swizzle (m204)
__device__ __forceinline__ void xcd_swizzle(int& bx, int& by) {
    int gx = gridDim.x;
    int nwg = gx * gridDim.y;
    int l = blockIdx.y * gx + blockIdx.x;
    int q = nwg >> 3, r = nwg & 7;
    int xcd = l & 7, pos = l >> 3;
    int nl = (xcd < r ? xcd * (q + 1) : r * (q + 1) + (xcd - r) * q) + pos;
    by = nl / gx;
    bx = nl - by * gx;
}

// ---------------- weight transpose + bf16 cast: wt[n*K+k] = w[(k0+k)*N+n] ----------------
__global__ void transpose_to_bf16(const float* __restrict__ w, __hip_bfloat16* __restrict__ wt,
                                  int K, int N, int k0) {
    int idx = blockIdx.x * blockDim.x + threadIdx.x;
    if (idx >= K * N) return;
    int n = idx / K;
    int k = idx - n * K;
    wt[idx] = __float2bfloat16(w[(size_t)(k0 + k) * N + n]);
}

// ---------------- sincos positional embedding ----------------
__global__ void embed_kernel(const float* __restrict__ pos, __hip_bfloat16* __restrict__ outp,
                             int n, int stride, int coloff) {
    int idx = blockIdx.x * blockDim.x + threadIdx.x;
    if (idx >= n * 96) return;
    int nn = idx / 96;
    int rr = idx - nn * 96;
    int d = rr >> 5;
    int k = rr & 31;
    float v = pos[nn * 3 + d];
    float omega = expf(-0.28782313662425575f * (float)k);  // ln(10000)/32
    float a = v * omega;
    __hip_bfloat16* o = outp + (size_t)nn * stride + coloff + d * 64 + k;
    o[0]  = __float2bfloat16(sinf(a));
    o[32] = __float2bfloat16(cosf(a));
}

// ---------------- layer 1: h1 = gelu(x @ w1 + b1), K=16 ----------------
__global__ void lin1_kernel(const float* __restrict__ x, const float* __restrict__ w,
                            const float* __restrict__ b, __hip_bfloat16* __restrict__ h1) {
    int idx = blockIdx.x * blockDim.x + threadIdx.x;
    if (idx >= NMESH * HID) return;
    int m = idx / HID;
    int n = idx - m * HID;
    float acc = b[n];
    const float* xr = x + m * 16;
    #pragma unroll
    for (int k = 0; k < 16; k++) acc = fmaf(xr[k], w[k * HID + n], acc);
    h1[idx] = __float2bfloat16(gelu_f(acc));
}

// ======================================================================
// 128x128-tile bf16 MFMA GEMM (round-11/12 proven body).
// 3-buffer counted-vmcnt pipeline, pre-swizzled global_load_lds
// (measured: 0 bank conflicts, no spill). C = act(A @ Wt^T + bias).
// ======================================================================
template<bool GELU, bool F32OUT>
__launch_bounds__(256, 3)
__global__ void mfma_gemm(const __hip_bfloat16* __restrict__ A,
                          const __hip_bfloat16* __restrict__ Wt,
                          const float* __restrict__ bias,
                          void* __restrict__ Cv,
                          int M, int N, int K, int ldc) {
    __shared__ __align__(16) __hip_bfloat16 As[3][4096];
    __shared__ __align__(16) __hip_bfloat16 Bs[3][4096];

    const int t = threadIdx.x;
    const int lane = t & 63;
    const int wave = t >> 6;
    const int wm0 = (wave >> 1) * 64;
    const int wn0 = (wave & 1) * 64;

    int bx, by;
    xcd_swizzle(bx, by);
    const int row0 = by * 128;
    const int col0 = bx * 128;

    const int rS0 = t >> 2;
    const int rS1 = rS0 + 64;
    const int kcS = (t & 3) ^ ((t >> 3) & 3);

    const __hip_bfloat16* aP0 = A + (size_t)min(row0 + rS0, M - 1) * K;
    const __hip_bfloat16* aP1 = A + (size_t)min(row0 + rS1, M - 1) * K;
    const __hip_bfloat16* bP0 = Wt + (size_t)(col0 + rS0) * K;
    const __hip_bfloat16* bP1 = Wt + (size_t)(col0 + rS1) * K;

    const int off0 = (wave * 64) * 16;
    const int off1 = (256 + wave * 64) * 16;

    f32x4 acc[4][4] = {};

    const int kq = lane >> 4;
    const int lr = lane & 15;
    const int kqx = kq ^ ((lr >> 1) & 3);
    const int rdA = (wm0 + lr) * 32 + kqx * 8;
    const int rdB = (wn0 + lr) * 32 + kqx * 8;

    const int nsteps = K >> 5;

    auto stage = [&](int ks, int buf) {
        int k = ks * 32 + kcS * 8;
        load_lds16(aP0 + k, (char*)As[buf] + off0);
        load_lds16(aP1 + k, (char*)As[buf] + off1);
        load_lds16(bP0 + k, (char*)Bs[buf] + off0);
        load_lds16(bP1 + k, (char*)Bs[buf] + off1);
    };

    stage(0, 0);
    stage(1, 1);

    int cur = 0;
    int stg = 2;
    for (int ks = 0; ks < nsteps; ks++) {
        if (ks + 1 < nsteps) {
            asm volatile("s_waitcnt vmcnt(4)" ::: "memory");
        } else {
            asm volatile("s_waitcnt vmcnt(0)" ::: "memory");
        }
        __builtin_amdgcn_s_barrier();
        if (ks + 2 < nsteps) stage(ks + 2, stg);

        bfrag aF[4], bF[4];
        #pragma unroll
        for (int i = 0; i < 4; i++) {
            aF[i] = *reinterpret_cast<const bfrag*>(&As[cur][rdA + i * 512]);
            bF[i] = *reinterpret_cast<const bfrag*>(&Bs[cur][rdB + i * 512]);
        }
        asm volatile("s_waitcnt lgkmcnt(0)" ::: "memory");
        __builtin_amdgcn_sched_barrier(0);
        __builtin_amdgcn_s_setprio(1);
        #pragma unroll
        for (int i = 0; i < 4; i++) {
            #pragma unroll
            for (int j = 0; j < 4; j++) {
                acc[i][j] = __builtin_amdgcn_mfma_f32_16x16x32_bf16(aF[i], bF[j], acc[i][j], 0, 0, 0);
            }
        }
        __builtin_amdgcn_s_setprio(0);

        cur = (cur == 2) ? 0 : cur + 1;
        stg = (stg == 2) ? 0 : stg + 1;
    }

    #pragma unroll
    for (int i = 0; i < 4; i++) {
        #pragma unroll
        for (int j = 0; j < 4; j++) {
            #pragma unroll
            for (int r = 0; r < 4; r++) {
                int row = row0 + wm0 + i * 16 + kq * 4 + r;
                int col = col0 + wn0 + j * 16 + lr;
                if (row < M) {
                    float v = acc[i][j][r] + bias[col];
                    if constexpr (GELU) v = gelu_f(v);
                    if constexpr (F32OUT)
                        ((float*)Cv)[(size_t)row * ldc + col] = v;
                    else
                        ((__hip_bfloat16*)Cv)[(size_t)row * ldc + col] = __float2bfloat16(v);
                }
            }
        }
    }
}

// ---------------- m1 fuse: m1c[e] = gelu(U[mesh_idx[e]] + V[grid_idx[e]]) ----------------
__global__ void fuse_m1(const __hip_bfloat16* __restrict__ U, const __hip_bfloat16* __restrict__ V,
                        const int* __restrict__ edges, int e0, int ne,
                        __hip_bfloat16* __restrict__ m1c) {
    int idx = blockIdx.x * blockDim.x + threadIdx.x;
    if (idx >= ne * 96) return;
    int e = idx / 96;
    int c8 = (idx - e * 96) * 8;
    int ge = e0 + e;
    int mi = edges[2 * ge + 1];
    int gi = edges[2 * ge + 0];
    bfrag u = *reinterpret_cast<const bfrag*>(U + (size_t)mi * 768 + c8);
    bfrag v = *reinterpret_cast<const bfrag*>(V + (size_t)gi * 768 + c8);
    bfrag o;
    #pragma unroll
    for (int i = 0; i < 8; i++) {
        unsigned short ub = (unsigned short)u[i], vb = (unsigned short)v[i];
        float a = __bfloat162float(*(__hip_bfloat16*)&ub) + __bfloat162float(*(__hip_bfloat16*)&vb);
        a = gelu_f(a);
        __hip_bfloat16 hb = __float2bfloat16(a);
        o[i] = *(short*)&hb;
    }
    *reinterpret_cast<bfrag*>(m1c + (size_t)e * 768 + c8) = o;
}

// ---------------- per-chunk 768-wide f32 segment partial sums ----------------
__global__ void seg768(const int* __restrict__ edges, int e0, int e1,
                       const __hip_bfloat16* __restrict__ m2c, float* __restrict__ sums) {
    int g = blockIdx.x;
    int l = e0, r = e1;
    while (l < r) { int m = (l + r) >> 1; if (edges[2 * m] < g) l = m + 1; else r = m; }
    int lo = l;
    r = e1;
    while (l < r) { int m = (l + r) >> 1; if (edges[2 * m] <= g) l = m + 1; else r = m; }
    int hi = l;
    if (lo >= hi) return;

    int c = threadIdx.x;   // 256 threads, 3 cols each
    float s0 = 0.f, s1 = 0.f, s2 = 0.f;
    for (int e = lo; e < hi; e++) {
        const __hip_bfloat16* rp = m2c + (size_t)(e - e0) * 768;
        s0 += __bfloat162float(rp[c]);
        s1 += __bfloat162float(rp[c + 256]);
        s2 += __bfloat162float(rp[c + 512]);
    }
    float* srow = sums + (size_t)g * 768;
    srow[c] += s0;
    srow[c + 256] += s1;
    srow[c + 512] += s2;
}

// ---------------- per-grid-cell edge count ----------------
__global__ void calc_cnt(const int* __restrict__ edges, int* __restrict__ cnt) {
    int g = blockIdx.x * blockDim.x + threadIdx.x;
    if (g >= GRIDN) return;
    int l = 0, r = NEDGE;
    while (l < r) { int m = (l + r) >> 1; if (edges[2 * m] < g) l = m + 1; else r = m; }
    int lo = l;
    r = NEDGE;
    while (l < r) { int m = (l + r) >> 1; if (edges[2 * m] <= g) l = m + 1; else r = m; }
    cnt[g] = l - lo;
}

// ---------------- meanM2 = bf16(sums / max(cnt,1)) ----------------
__global__ void mean_bf16(const float* __restrict__ sums, const int* __restrict__ cnt,
                          __hip_bfloat16* __restrict__ mm) {
    int idx = blockIdx.x * blockDim.x + threadIdx.x;
    int base = idx * 4;
    if (base >= GRIDN * 768) return;
    int g = base / 768;
    float inv = 1.0f / (float)max(cnt[g], 1);
    float4 v = *reinterpret_cast<const float4*>(sums + base);
    __hip_bfloat16 o[4] = {__float2bfloat16(v.x * inv), __float2bfloat16(v.y * inv),
                           __float2bfloat16(v.z * inv), __float2bfloat16(v.w * inv)};
    *reinterpret_cast<uint2*>(mm + base) = *reinterpret_cast<const uint2*>(o);
}

// ---------------- zero output rows of empty segments (bias added unconditionally) ----------------
__global__ void fix_empty(const int* __restrict__ cnt, float* __restrict__ out) {
    int g = blockIdx.x * blockDim.x + threadIdx.x;
    if (g >= GRIDN || cnt[g] != 0) return;
    float* row = out + (size_t)g * HID;
    for (int c = 0; c < HID; c++) row[c] = 0.f;
}

// ---------------- fallback: 384-wide seg machinery (round-12 proven) ----------------
__global__ void seg_partial(const int* __restrict__ edges, int e0, int e1,
                            const __hip_bfloat16* __restrict__ m3c, float* __restrict__ out) {
    int g = blockIdx.x;
    int l = e0, r = e1;
    while (l < r) { int mid = (l + r) >> 1; if (edges[2 * mid] < g) l = mid + 1; else r = mid; }
    int lo = l;
    r = e1;
    while (l < r) { int mid = (l + r) >> 1; if (edges[2 * mid] <= g) l = mid + 1; else r = mid; }
    int hi = l;
    if (lo >= hi) return;
    int c = threadIdx.x;
    float s0 = 0.f, s1 = 0.f, s2 = 0.f;
    for (int e = lo; e < hi; e++) {
        const __hip_bfloat16* rp = m3c + (size_t)(e - e0) * HID;
        s0 += __bfloat162float(rp[c]);
        s1 += __bfloat162float(rp[c + 128]);
        s2 += __bfloat162float(rp[c + 256]);
    }
    float* orow = out + (size_t)g * HID;
    orow[c] += s0;
    orow[c + 128] += s1;
    orow[c + 256] += s2;
}

__global__ void seg_div(const int* __restrict__ edges, float* __restrict__ out) {
    int g = blockIdx.x;
    int l = 0, r = NEDGE;
    while (l < r) { int mid = (l + r) >> 1; if (edges[2 * mid] < g) l = mid + 1; else r = mid; }
    int lo = l;
    r = NEDGE;
    while (l < r) { int mid = (l + r) >> 1; if (edges[2 * mid] <= g) l = mid + 1; else r = mid; }
    int cnt = l - lo;
    float inv = 1.0f / (float)max(cnt, 1);
    int c = threadIdx.x;
    float* orow = out + (size_t)g * HID;
    orow[c] *= inv;
    orow[c + 128] *= inv;
    orow[c + 256] *= inv;
}

extern "C" void kernel_launch(void* const* d_in, const int* in_sizes, int n_in,
                              void* d_out, int out_size, void* d_ws, size_t ws_size,
                              hipStream_t stream) {
    const float* x        = (const float*)d_in[0];
    const float* mesh_pos = (const float*)d_in[1];
    const float* grid_pos = (const float*)d_in[2];
    const int*   edges    = (const int*)d_in[3];
    const float* w1  = (const float*)d_in[4];
    const float* b1  = (const float*)d_in[5];
    const float* w2  = (const float*)d_in[6];
    const float* b2  = (const float*)d_in[7];
    const float* w3  = (const float*)d_in[8];
    const float* b3  = (const float*)d_in[9];
    const float* wm1 = (const float*)d_in[10];
    const float* bm1 = (const float*)d_in[11];
    const float* wm2 = (const float*)d_in[12];
    const float* bm2 = (const float*)d_in[13];
    const float* wm3 = (const float*)d_in[14];
    const float* bm3 = (const float*)d_in[15];
    float* out = (float*)d_out;

    auto rnd = [](size_t b) { return (b + 255) & ~(size_t)255; };
    const size_t wbytes = rnd((size_t)384 * 384 * 2) * 2 + rnd((size_t)768 * 576 * 2) +
                          rnd((size_t)768 * 192 * 2) + rnd((size_t)768 * 768 * 2) +
                          rnd((size_t)384 * 768 * 2) + rnd(768 * 4) + rnd((size_t)GRIDN * 4);
    const size_t szU    = rnd((size_t)NMESH * 768 * 2);     // 76.8 MB
    const size_t szV    = rnd((size_t)GRIDN * 768 * 2);     // 50.33 MB
    const size_t szMesh = rnd((size_t)NMESH * 576 * 2);     // 57.6 MB
    const size_t szGrid = rnd((size_t)GRIDN * 192 * 2);     // 12.58 MB
    const size_t szSums = rnd((size_t)GRIDN * 768 * 4);     // 100.66 MB (>= szMesh+szGrid)

    // fold path @ CH=16384: weights + U + V + sums + 2 chunk bufs  ~= 282 MB
    const size_t NEED_FOLD = wbytes + szU + szV + szSums + 2 * rnd((size_t)16384 * 768 * 2);

    char* p = (char*)d_ws;
    auto alloc = [&](size_t b) { char* r = p; p += (b + 255) & ~(size_t)255; return r; };

    // common weight/embed prep allocations (identical in both paths)
    __hip_bfloat16* wt2   = (__hip_bfloat16*)alloc((size_t)384 * 384 * 2);
    __hip_bfloat16* wt3   = (__hip_bfloat16*)alloc((size_t)384 * 384 * 2);
    __hip_bfloat16* wtm1u = (__hip_bfloat16*)alloc((size_t)768 * 576 * 2);
    __hip_bfloat16* wtm1v = (__hip_bfloat16*)alloc((size_t)768 * 192 * 2);
    __hip_bfloat16* wtm2  = (__hip_bfloat16*)alloc((size_t)768 * 768 * 2);
    __hip_bfloat16* wtm3  = (__hip_bfloat16*)alloc((size_t)384 * 768 * 2);
    float* zeros          = (float*)alloc(768 * 4);
    int* cnt              = (int*)alloc((size_t)GRIDN * 4);
    char* Ur              = alloc(szU);
    char* Vr              = alloc(szV);

    __hip_bfloat16* U  = (__hip_bfloat16*)Ur;
    __hip_bfloat16* V  = (__hip_bfloat16*)Vr;
    __hip_bfloat16* h1 = (__hip_bfloat16*)Ur;                 // [0, 38.4 MB)
    __hip_bfloat16* h2 = (__hip_bfloat16*)(Ur + 38400000);    // [38.4, 76.8)

    hipMemsetAsync(zeros, 0, 768 * 4, stream);

    transpose_to_bf16<<<(384 * 384 + 255) / 256, 256, 0, stream>>>(w2, wt2, 384, 384, 0);
    transpose_to_bf16<<<(384 * 384 + 255) / 256, 256, 0, stream>>>(w3, wt3, 384, 384, 0);
    transpose_to_bf16<<<(768 * 576 + 255) / 256, 256, 0, stream>>>(wm1, wtm1u, 576, 768, 0);
    transpose_to_bf16<<<(768 * 192 + 255) / 256, 256, 0, stream>>>(wm1, wtm1v, 192, 768, 576);
    transpose_to_bf16<<<(768 * 768 + 255) / 256, 256, 0, stream>>>(wm2, wtm2, 768, 768, 0);
    transpose_to_bf16<<<(768 * 384 + 255) / 256, 256, 0, stream>>>(wm3, wtm3, 768, 384, 0);

    if (ws_size >= NEED_FOLD) {
        // ================= FOLD PATH: U/V + linear-m3 folding, CH=16384 =================
        const int CH = 16384;
        const int NCH = NEDGE / CH;
        char* SR = alloc(szSums);                       // sums region (embeds overlay here)
        char* CA = alloc(2 * rnd((size_t)CH * 768 * 2));

        float* sums           = (float*)SR;
        __hip_bfloat16* meshf = (__hip_bfloat16*)SR;           // dead after U-GEMM
        __hip_bfloat16* gridf = (__hip_bfloat16*)(SR + szMesh);// dead after V-GEMM
        __hip_bfloat16* m1c   = (__hip_bfloat16*)CA;
        __hip_bfloat16* m2c   = (__hip_bfloat16*)(CA + rnd((size_t)CH * 768 * 2));
        __hip_bfloat16* meanM2= (__hip_bfloat16*)CA;           // spans m1c+m2c (both dead)

        embed_kernel<<<(NMESH * 96 + 255) / 256, 256, 0, stream>>>(mesh_pos, meshf, NMESH, 576, 384);
        embed_kernel<<<(GRIDN * 96 + 255) / 256, 256, 0, stream>>>(grid_pos, gridf, GRIDN, 192, 0);

        lin1_kernel<<<(NMESH * HID + 255) / 256, 256, 0, stream>>>(x, w1, b1, h1);

        mfma_gemm<true, false><<<dim3(3, 391), 256, 0, stream>>>(
            h1, wt2, b2, h2, NMESH, 384, 384, 384);
        mfma_gemm<false, false><<<dim3(3, 391), 256, 0, stream>>>(
            h2, wt3, b3, meshf, NMESH, 384, 384, 576);
        // U = meshf @ wm1[:576] + bm1  (overwrites h1/h2 -- dead)
        mfma_gemm<false, false><<<dim3(6, 391), 256, 0, stream>>>(
            meshf, wtm1u, bm1, U, NMESH, 768, 576, 768);
        // V = gridf @ wm1[576:]
        mfma_gemm<false, false><<<dim3(6, 256), 256, 0, stream>>>(
            gridf, wtm1v, zeros, V, GRIDN, 768, 192, 768);

        hipMemsetAsync(sums, 0, (size_t)GRIDN * 768 * 4, stream);  // embeds now dead

        for (int c = 0; c < NCH; c++) {
            int e0 = c * CH;
            fuse_m1<<<(CH * 96 + 255) / 256, 256, 0, stream>>>(U, V, edges, e0, CH, m1c);
            mfma_gemm<true, false><<<dim3(6, CH / 128), 256, 0, stream>>>(
                m1c, wtm2, bm2, m2c, CH, 768, 768, 768);
            seg768<<<GRIDN, 256, 0, stream>>>(edges, e0, e0 + CH, m2c, sums);
        }

        calc_cnt<<<(GRIDN + 255) / 256, 256, 0, stream>>>(edges, cnt);
        mean_bf16<<<(GRIDN * 768 / 4 + 255) / 256, 256, 0, stream>>>(sums, cnt, meanM2);
        // out = meanM2 @ wm3 + bm3   (f32, direct to d_out; covers all rows)
        mfma_gemm<false, true><<<dim3(3, 256), 256, 0, stream>>>(
            meanM2, wtm3, bm3, out, GRIDN, 384, 768, 384);
        fix_empty<<<(GRIDN + 255) / 256, 256, 0, stream>>>(cnt, out);
    } else {
        // ================= FALLBACK: round-12 proven U/V path, CH=32768 (~231 MB) =================
        const int CH = 32768;
        const int NCH = NEDGE / CH;
        char* CA = alloc(2 * rnd((size_t)CH * 768 * 2));   // also hosts meshf+gridf (70.2 < 100.7)

        __hip_bfloat16* meshf = (__hip_bfloat16*)CA;
        __hip_bfloat16* gridf = (__hip_bfloat16*)(CA + szMesh);
        __hip_bfloat16* m1c   = (__hip_bfloat16*)CA;
        __hip_bfloat16* m2c   = (__hip_bfloat16*)(CA + rnd((size_t)CH * 768 * 2));
        __hip_bfloat16* m3c   = m1c;

        hipMemsetAsync(out, 0, (size_t)GRIDN * HID * 4, stream);

        embed_kernel<<<(NMESH * 96 + 255) / 256, 256, 0, stream>>>(mesh_pos, meshf, NMESH, 576, 384);
        embed_kernel<<<(GRIDN * 96 + 255) / 256, 256, 0, stream>>>(grid_pos, gridf, GRIDN, 192, 0);

        lin1_kernel<<<(NMESH * HID + 255) / 256, 256, 0, stream>>>(x, w1, b1, h1);

        mfma_gemm<true, false><<<dim3(3, 391), 256, 0, stream>>>(
            h1, wt2, b2, h2, NMESH, 384, 384, 384);
        mfma_gemm<false, false><<<dim3(3, 391), 256, 0, stream>>>(
            h2, wt3, b3, meshf, NMESH, 384, 384, 576);
        mfma_gemm<false, false><<<dim3(6, 391), 256, 0, stream>>>(
            meshf, wtm1u, bm1, U, NMESH, 768, 576, 768);
        mfma_gemm<false, false><<<dim3(6, 256), 256, 0, stream>>>(
            gridf, wtm1v, zeros, V, GRIDN, 768, 192, 768);

        for (int c = 0; c < NCH; c++) {
            int e0 = c * CH;
            fuse_m1<<<(CH * 96 + 255) / 256, 256, 0, stream>>>(U, V, edges, e0, CH, m1c);
            mfma_gemm<true, false><<<dim3(6, CH / 128), 256, 0, stream>>>(
                m1c, wtm2, bm2, m2c, CH, 768, 768, 768);
            mfma_gemm<false, false><<<dim3(3, CH / 128), 256, 0, stream>>>(
                m2c, wtm3, bm3, m3c, CH, 384, 768, 384);
            seg_partial<<<GRIDN, 128, 0, stream>>>(edges, e0, e0 + CH, m3c, out);
        }

        seg_div<<<GRIDN, 128, 0, stream>>>(edges, out);
    }
}